// Round 14
// baseline (313.971 us; speedup 1.0000x reference)
//
#include <hip/hip_runtime.h>

#define NN 10000
#define NE 320000
#define HD 256
#define NL 3

typedef unsigned short ushort_t;
typedef __attribute__((ext_vector_type(8))) short bf16x8;
typedef __attribute__((ext_vector_type(4))) float f32x4;

#define MFMA __builtin_amdgcn_mfma_f32_16x16x32_bf16

#define SCHEDPIN() __builtin_amdgcn_sched_barrier(0)
// lgkm-only barrier: does NOT drain vmcnt, so in-flight register prefetches survive
#define LGKMBAR() do { asm volatile("s_waitcnt lgkmcnt(0)" ::: "memory"); \
                       __builtin_amdgcn_s_barrier(); __builtin_amdgcn_sched_barrier(0); } while (0)

__device__ __forceinline__ unsigned short f2bf(float x) {
    unsigned u = __float_as_uint(x);
    unsigned rounding = 0x7FFFu + ((u >> 16) & 1u);
    return (unsigned short)((u + rounding) >> 16);
}
__device__ __forceinline__ float bf2f(unsigned short u) {
    return __uint_as_float(((unsigned)u) << 16);
}

// ---------------- CSR build ----------------

__global__ void hist_deg(const int* __restrict__ dst, int* __restrict__ deg, int E) {
    int e = blockIdx.x * blockDim.x + threadIdx.x;
    if (e < E) atomicAdd(&deg[dst[e]], 1);
}

__global__ __launch_bounds__(1024) void scan_csr(const int* __restrict__ deg,
                                                 int* __restrict__ row_start,
                                                 int* __restrict__ cursor,
                                                 float* __restrict__ degf,
                                                 float* __restrict__ gsum, int n) {
    __shared__ int wsum[16];
    __shared__ int carry_s;
    int tid = threadIdx.x, lane = tid & 63, wid = tid >> 6;
    if (tid < HD) gsum[tid] = 0.f;
    if (tid == 0) carry_s = 0;
    __syncthreads();
    for (int base = 0; base < n; base += 1024) {
        int i = base + tid;
        int v = (i < n) ? deg[i] : 0;
        int s = v;
        #pragma unroll
        for (int off = 1; off < 64; off <<= 1) {
            int t = __shfl_up(s, off);
            if (lane >= off) s += t;
        }
        if (lane == 63) wsum[wid] = s;
        __syncthreads();
        if (wid == 0 && lane < 16) {
            int ws = wsum[lane];
            #pragma unroll
            for (int off = 1; off < 16; off <<= 1) {
                int t = __shfl_up(ws, off);
                if (lane >= off) ws += t;
            }
            wsum[lane] = ws;
        }
        __syncthreads();
        int carry = carry_s;
        int wpre = (wid > 0) ? wsum[wid - 1] : 0;
        int incl = carry + wpre + s;
        int excl = incl - v;
        if (i < n) { row_start[i] = excl; cursor[i] = excl; degf[i] = (float)v; }
        __syncthreads();
        if (tid == 1023) carry_s = incl;
        __syncthreads();
    }
    if (tid == 0) row_start[n] = carry_s;
}

__global__ void scatter_src(const int* __restrict__ src, const int* __restrict__ dst,
                            int* __restrict__ cursor, int* __restrict__ src_sorted, int E) {
    int e = blockIdx.x * blockDim.x + threadIdx.x;
    if (e < E) {
        int pos = atomicAdd(&cursor[dst[e]], 1);
        src_sorted[pos] = src[e];
    }
}

// ---------------- weight prep ----------------
// mode 0: straight cast; mode 1: transpose cast row-major;
// mode 2: transpose + K-sliced tile: ushort idx (k,col) = (k>>5)*8192 + col*32 + (k&31)

struct TDesc { const float* src; ushort_t* dst; int mode; };
struct TArgs { TDesc d[20]; };

__global__ __launch_bounds__(256) void conv_t(TArgs args) {
    __shared__ ushort_t tile[64][65];
    const float* src = args.d[blockIdx.y].src;
    ushort_t* dst = args.d[blockIdx.y].dst;
    int mode = args.d[blockIdx.y].mode;
    int t = blockIdx.x;
    int r0 = (t >> 2) * 64, c0 = (t & 3) * 64;
    int tid = threadIdx.x;
    int rr = tid >> 4, cc4 = (tid & 15) * 4;
    if (mode == 0) {
        #pragma unroll
        for (int i = 0; i < 4; ++i) {
            int r = r0 + rr + i * 16;
            float4 v = *(const float4*)(src + (size_t)r * HD + c0 + cc4);
            ushort4 o = { f2bf(v.x), f2bf(v.y), f2bf(v.z), f2bf(v.w) };
            *(ushort4*)(dst + (size_t)r * HD + c0 + cc4) = o;
        }
        return;
    }
    #pragma unroll
    for (int i = 0; i < 4; ++i) {
        int r = rr + i * 16;
        float4 v = *(const float4*)(src + (size_t)(r0 + r) * HD + c0 + cc4);
        tile[cc4 + 0][r] = f2bf(v.x);
        tile[cc4 + 1][r] = f2bf(v.y);
        tile[cc4 + 2][r] = f2bf(v.z);
        tile[cc4 + 3][r] = f2bf(v.w);
    }
    __syncthreads();
    #pragma unroll
    for (int i = 0; i < 4; ++i) {
        int c = rr + i * 16;
        ushort4 o = { tile[c][cc4], tile[c][cc4 + 1], tile[c][cc4 + 2], tile[c][cc4 + 3] };
        if (mode == 1) {
            *(ushort4*)(dst + (size_t)(c0 + c) * HD + r0 + cc4) = o;
        } else {
            int col = c0 + c;
            int k = r0 + cc4;
            *(ushort4*)(dst + (size_t)(k >> 5) * 8192 + col * 32 + (k & 31)) = o;
        }
    }
}

// nf -> bf16 A-tiles: idx = blk*4096 + (col>>5)*512 + row*32 + (col&31)
__global__ __launch_bounds__(256) void cast_nf_tiled(const float* __restrict__ src,
                                                     ushort_t* __restrict__ dst) {
    int blk = blockIdx.x;
    int row = threadIdx.x >> 4, g = threadIdx.x & 15;
    const float* sp = src + ((size_t)blk * 16 + row) * HD + g * 16;
    ushort_t* dp = dst + (size_t)blk * 4096 + (g >> 1) * 512 + row * 32 + (g & 1) * 16;
    #pragma unroll
    for (int j = 0; j < 4; ++j) {
        float4 v = *(const float4*)(sp + j * 4);
        ushort4 o = { f2bf(v.x), f2bf(v.y), f2bf(v.z), f2bf(v.w) };
        *(ushort4*)(dp + j * 4) = o;
    }
}

__global__ __launch_bounds__(256) void bias_compose(const float* __restrict__ mb2,
                                                    const float* __restrict__ uw1,
                                                    float* __restrict__ out) {
    int l = blockIdx.x, c = threadIdx.x;
    const float* b2l = mb2 + (size_t)l * HD;
    const float* u1b = uw1 + (size_t)l * 2 * HD * HD + (size_t)HD * HD;
    float s = 0.f;
    for (int k = 0; k < HD; ++k) s += b2l[k] * u1b[(size_t)k * HD + c];
    out[(size_t)l * HD + c] = s;
}

// w2uT[l] = (w2[l]@u1b[l])^T, written in mode-2 tiled layout (first idx n, second k)
__global__ __launch_bounds__(256) void gemm_w2u(
    const ushort_t* __restrict__ Abase, const ushort_t* __restrict__ Btbase,
    ushort_t* __restrict__ outBase)
{
    const ushort_t* A  = Abase  + (size_t)blockIdx.z * HD * HD;
    const ushort_t* Bt = Btbase + (size_t)blockIdx.z * HD * HD;
    ushort_t* outB     = outBase + (size_t)blockIdx.z * HD * HD;
    int tid = threadIdx.x;
    int wid = tid >> 6, lane = tid & 63;
    int wm = wid >> 1, wn = wid & 1;
    int row0 = blockIdx.x * 64 + wm * 32;
    int col0 = blockIdx.y * 64 + wn * 32;
    int lm = lane & 15, lk = (lane >> 4) * 8;
    f32x4 acc[2][2] = {};
    const ushort_t* a0p = A + (size_t)(row0 + lm) * HD + lk;
    const ushort_t* a1p = A + (size_t)(row0 + 16 + lm) * HD + lk;
    const ushort_t* b0p = Bt + (size_t)(col0 + lm) * HD + lk;
    const ushort_t* b1p = Bt + (size_t)(col0 + 16 + lm) * HD + lk;
    #pragma unroll
    for (int k0 = 0; k0 < HD; k0 += 32) {
        bf16x8 a0 = *(const bf16x8*)(a0p + k0);
        bf16x8 a1 = *(const bf16x8*)(a1p + k0);
        bf16x8 b0 = *(const bf16x8*)(b0p + k0);
        bf16x8 b1 = *(const bf16x8*)(b1p + k0);
        acc[0][0] = MFMA(a0, b0, acc[0][0], 0, 0, 0);
        acc[0][1] = MFMA(a0, b1, acc[0][1], 0, 0, 0);
        acc[1][0] = MFMA(a1, b0, acc[1][0], 0, 0, 0);
        acc[1][1] = MFMA(a1, b1, acc[1][1], 0, 0, 0);
    }
    int orow = (lane >> 4) * 4;
    #pragma unroll
    for (int mi = 0; mi < 2; ++mi)
        #pragma unroll
        for (int r = 0; r < 4; ++r) {
            int row = row0 + mi * 16 + orow + r;
            #pragma unroll
            for (int ni = 0; ni < 2; ++ni) {
                int col = col0 + ni * 16 + lm;
                outB[(size_t)(col >> 5) * 8192 + row * 32 + (col & 31)] = f2bf(acc[mi][ni][r]);
            }
        }
}

// ---------------- LDS swizzle for hid [16 rows][512B] ----------------
__device__ __forceinline__ int swz(int row, int byte_in_row) {
    return row * 512 + (byte_in_row ^ ((row & 7) << 4));
}

// ---------------- fused encoder + layer-0 P/Q (register-staged weights) ----------------

__global__ __launch_bounds__(512, 4) void enc_pq(
    const ushort_t* __restrict__ Anf, const ushort_t* __restrict__ B1t,
    const ushort_t* __restrict__ B2t,
    const float* __restrict__ b1, const float* __restrict__ b2,
    const ushort_t* __restrict__ Pw1t, const ushort_t* __restrict__ Pw1b,
    const float* __restrict__ pqb1,
    float* __restrict__ xF, ushort_t* __restrict__ xB,
    ushort_t* __restrict__ P, float* __restrict__ Q, int M)
{
    __shared__ char hid[16 * 512];
    int tid = threadIdx.x;
    int w = tid >> 6, lane = tid & 63;
    int lm = lane & 15, q = lane >> 4;
    int row0 = blockIdx.x * 16;
    int col0 = w * 32;
    int cA = col0 + lm, cB = col0 + 16 + lm;
    size_t boff = (size_t)(col0 + lm) * 64 + q * 16;

    auto ldW = [&](const ushort_t* Wt, int s, int ni) -> bf16x8 {
        return *(const bf16x8*)((const char*)Wt + (size_t)s * 16384 + boff + ni * 1024);
    };
    const ushort_t* ap = Anf + (size_t)blockIdx.x * 4096 + lm * 32 + q * 8;

    bf16x8 wb[2][2], axr[2];
    #pragma unroll
    for (int s = 0; s < 2; ++s) {
        wb[s][0] = ldW(B1t, s, 0); wb[s][1] = ldW(B1t, s, 1);
        axr[s] = *(const bf16x8*)(ap + s * 512);
    }
    float b1v[2] = { b1[cA], b1[cB] };
    float b2v[2] = { b2[cA], b2[cB] };

    f32x4 acc[2] = {};
    #pragma unroll
    for (int j = 0; j < 8; ++j) {
        int p = j & 1;
        acc[0] = MFMA(axr[p], wb[p][0], acc[0], 0, 0, 0);
        acc[1] = MFMA(axr[p], wb[p][1], acc[1], 0, 0, 0);
        if (j < 6) {
            wb[p][0] = ldW(B1t, j + 2, 0); wb[p][1] = ldW(B1t, j + 2, 1);
            axr[p] = *(const bf16x8*)(ap + (j + 2) * 512);
        }
    }

    bf16x8 vw[2][2];
    #pragma unroll
    for (int s = 0; s < 2; ++s) { vw[s][0] = ldW(B2t, s, 0); vw[s][1] = ldW(B2t, s, 1); }

    #pragma unroll
    for (int ni = 0; ni < 2; ++ni) {
        int col = col0 + 16 * ni + lm;
        #pragma unroll
        for (int r = 0; r < 4; ++r) {
            int row = 4 * q + r;
            float v = fmaxf(acc[ni][r] + b1v[ni], 0.f);
            *(ushort_t*)(hid + swz(row, col * 2)) = f2bf(v);
        }
    }
    LGKMBAR();

    f32x4 acc2[2] = {};
    #pragma unroll
    for (int j = 0; j < 8; ++j) {
        int p = j & 1;
        int bk = (j * 32 + q * 8) * 2;
        bf16x8 a = *(const bf16x8*)(hid + swz(lm, bk));
        acc2[0] = MFMA(a, vw[p][0], acc2[0], 0, 0, 0);
        acc2[1] = MFMA(a, vw[p][1], acc2[1], 0, 0, 0);
        if (j < 6) { vw[p][0] = ldW(B2t, j + 2, 0); vw[p][1] = ldW(B2t, j + 2, 1); }
    }

    bf16x8 pw[2][2], qw[2][2];
    #pragma unroll
    for (int s = 0; s < 2; ++s) {
        pw[s][0] = ldW(Pw1t, s, 0); pw[s][1] = ldW(Pw1t, s, 1);
        qw[s][0] = ldW(Pw1b, s, 0); qw[s][1] = ldW(Pw1b, s, 1);
    }
    float pqv[2] = { pqb1[cA], pqb1[cB] };
    LGKMBAR();
    int tbase = blockIdx.x * 4096 + w * 512;
    #pragma unroll
    for (int ni = 0; ni < 2; ++ni) {
        int col = col0 + 16 * ni + lm;
        #pragma unroll
        for (int r = 0; r < 4; ++r) {
            int row = 4 * q + r;
            int grow = row0 + row;
            float v = acc2[ni][r] + b2v[ni];
            *(ushort_t*)(hid + swz(row, col * 2)) = f2bf(v);
            xF[(size_t)grow * HD + col] = v;
            xB[tbase + row * 32 + 16 * ni + lm] = f2bf(v);
        }
    }
    LGKMBAR();

    f32x4 aP[2] = {}, aQ[2] = {};
    #pragma unroll
    for (int j = 0; j < 8; ++j) {
        int p = j & 1;
        int bk = (j * 32 + q * 8) * 2;
        bf16x8 a = *(const bf16x8*)(hid + swz(lm, bk));
        aP[0] = MFMA(a, pw[p][0], aP[0], 0, 0, 0);
        aP[1] = MFMA(a, pw[p][1], aP[1], 0, 0, 0);
        aQ[0] = MFMA(a, qw[p][0], aQ[0], 0, 0, 0);
        aQ[1] = MFMA(a, qw[p][1], aQ[1], 0, 0, 0);
        if (j < 6) {
            pw[p][0] = ldW(Pw1t, j + 2, 0); pw[p][1] = ldW(Pw1t, j + 2, 1);
            qw[p][0] = ldW(Pw1b, j + 2, 0); qw[p][1] = ldW(Pw1b, j + 2, 1);
        }
    }
    #pragma unroll
    for (int r = 0; r < 4; ++r) {
        int grow = row0 + 4 * q + r;
        #pragma unroll
        for (int ni = 0; ni < 2; ++ni) {
            int col = col0 + 16 * ni + lm;
            P[(size_t)grow * HD + col] = f2bf(aP[ni][r]);
            Q[(size_t)grow * HD + col] = aQ[ni][r] + pqv[ni];
        }
    }
}

// ---------------- fused gather + update + LN + next P/Q ----------------
// Wave w gathers Hagg for nodes {2w, 2w+1} into an 8 KB LDS tile (A-frag layout)
// while its pass-1 weight/A prefetches are in flight; then 3 GEMM passes as before.

__global__ __launch_bounds__(512, 4) void upd_ln(
    const ushort_t* __restrict__ xb,
    const ushort_t* __restrict__ Pin, float* __restrict__ Qf,
    const int* __restrict__ row_start, const int* __restrict__ srcs,
    const ushort_t* __restrict__ B1t, const ushort_t* __restrict__ B2t,
    const ushort_t* __restrict__ B3t,
    const float* __restrict__ degf,
    const float* __restrict__ b1, const float* __restrict__ bias2,
    const float* __restrict__ b3,
    const float* __restrict__ g, const float* __restrict__ bb,
    const ushort_t* __restrict__ Pw1t, const ushort_t* __restrict__ Pw1b,
    const float* __restrict__ pqb1,
    float* __restrict__ gsum,
    float* __restrict__ xF, ushort_t* __restrict__ xB,
    ushort_t* __restrict__ Pout, int M)
{
    __shared__ char hag[8 * 1024];     // [slice][16 rows][64B] A-frag layout
    __shared__ char hid[16 * 512];
    __shared__ float sS[8][16], sQ[8][16], muv[16], ivv[16];
    int tid = threadIdx.x;
    int w = tid >> 6, lane = tid & 63;
    int lm = lane & 15, q = lane >> 4;
    int row0 = blockIdx.x * 16;
    int col0 = w * 32;
    int cA = col0 + lm, cB = col0 + 16 + lm;
    size_t boff = (size_t)(col0 + lm) * 64 + q * 16;

    auto ldW = [&](const ushort_t* Wt, int s, int ni) -> bf16x8 {
        return *(const bf16x8*)((const char*)Wt + (size_t)s * 16384 + boff + ni * 1024);
    };
    const ushort_t* xp = xb + (size_t)blockIdx.x * 4096 + lm * 32 + q * 8;

    // pass-1+2 weight/A prologue ISSUED FIRST (flies under the gather)
    bf16x8 wb[2][2][2], axr[2];
    #pragma unroll
    for (int s = 0; s < 2; ++s) {
        wb[s][0][0] = ldW(B1t, s, 0); wb[s][0][1] = ldW(B1t, s, 1);
        wb[s][1][0] = ldW(B2t, s, 0); wb[s][1][1] = ldW(B2t, s, 1);
        axr[s] = *(const bf16x8*)(xp + s * 512);
    }
    SCHEDPIN();

    // Phase A: gather Hagg rows 2w, 2w+1 (64 lanes x 4 channels each)
    int c4 = lane * 4;
    #pragma unroll
    for (int t = 0; t < 2; ++t) {
        int lrow = 2 * w + t;
        int node = row0 + lrow;
        float4 qb = *(const float4*)(Qf + (size_t)node * HD + c4);
        float4 a4 = {0.f, 0.f, 0.f, 0.f};
        int j = row_start[node], e = row_start[node + 1];
        for (; j + 8 <= e; j += 8) {
            ushort4 pv[8];
            #pragma unroll
            for (int u = 0; u < 8; ++u) {
                int s = srcs[j + u];
                pv[u] = *(const ushort4*)(Pin + (size_t)s * HD + c4);
            }
            #pragma unroll
            for (int u = 0; u < 8; ++u) {
                a4.x += fmaxf(bf2f(pv[u].x) + qb.x, 0.f);
                a4.y += fmaxf(bf2f(pv[u].y) + qb.y, 0.f);
                a4.z += fmaxf(bf2f(pv[u].z) + qb.z, 0.f);
                a4.w += fmaxf(bf2f(pv[u].w) + qb.w, 0.f);
            }
        }
        for (; j < e; ++j) {
            int s = srcs[j];
            ushort4 p0 = *(const ushort4*)(Pin + (size_t)s * HD + c4);
            a4.x += fmaxf(bf2f(p0.x) + qb.x, 0.f);
            a4.y += fmaxf(bf2f(p0.y) + qb.y, 0.f);
            a4.z += fmaxf(bf2f(p0.z) + qb.z, 0.f);
            a4.w += fmaxf(bf2f(p0.w) + qb.w, 0.f);
        }
        ushort4 o = { f2bf(a4.x), f2bf(a4.y), f2bf(a4.z), f2bf(a4.w) };
        *(ushort4*)(hag + (c4 >> 5) * 1024 + lrow * 64 + (c4 & 31) * 2) = o;
    }
    float b1v[2] = { b1[cA], b1[cB] };
    float bzv[2] = { bias2[cA], bias2[cB] };
    float dgv[4];
    #pragma unroll
    for (int r = 0; r < 4; ++r) dgv[r] = degf[row0 + 4 * q + r];
    LGKMBAR();   // hag visible block-wide; weight prefetches stay in flight

    // ---- pass 1+2: acc = x@u1t + Hagg(LDS)@w2u ----
    f32x4 acc[2] = {};
    #pragma unroll
    for (int j = 0; j < 8; ++j) {
        int p = j & 1;
        bf16x8 ah = *(const bf16x8*)(hag + j * 1024 + lm * 64 + q * 16);
        acc[0] = MFMA(axr[p], wb[p][0][0], acc[0], 0, 0, 0);
        acc[0] = MFMA(ah, wb[p][1][0], acc[0], 0, 0, 0);
        acc[1] = MFMA(axr[p], wb[p][0][1], acc[1], 0, 0, 0);
        acc[1] = MFMA(ah, wb[p][1][1], acc[1], 0, 0, 0);
        if (j < 6) {
            wb[p][0][0] = ldW(B1t, j + 2, 0); wb[p][0][1] = ldW(B1t, j + 2, 1);
            wb[p][1][0] = ldW(B2t, j + 2, 0); wb[p][1][1] = ldW(B2t, j + 2, 1);
            axr[p] = *(const bf16x8*)(xp + (j + 2) * 512);
        }
    }

    // pass-3 weight prologue (in flight over hid build)
    bf16x8 uw[2][2];
    #pragma unroll
    for (int s = 0; s < 2; ++s) { uw[s][0] = ldW(B3t, s, 0); uw[s][1] = ldW(B3t, s, 1); }

    #pragma unroll
    for (int r = 0; r < 4; ++r) {
        int row = 4 * q + r;
        #pragma unroll
        for (int ni = 0; ni < 2; ++ni) {
            int col = col0 + 16 * ni + lm;
            float v = fmaxf(acc[ni][r] + b1v[ni] + dgv[r] * bzv[ni], 0.f);
            *(ushort_t*)(hid + swz(row, col * 2)) = f2bf(v);
        }
    }
    LGKMBAR();

    // epilogue scalars (overlap pass 3)
    float b3v[2] = { b3[cA], b3[cB] };
    float gv[2]  = { g[cA],  g[cB]  };
    float bbv[2] = { bb[cA], bb[cB] };
    float res[2][4];
    #pragma unroll
    for (int r = 0; r < 4; ++r) {
        int gr = row0 + 4 * q + r;
        res[0][r] = xF[(size_t)gr * HD + cA];
        res[1][r] = xF[(size_t)gr * HD + cB];
    }

    // ---- pass 3: upd = hid @ u2 ----
    f32x4 acc2[2] = {};
    #pragma unroll
    for (int j = 0; j < 8; ++j) {
        int p = j & 1;
        int bk = (j * 32 + q * 8) * 2;
        bf16x8 a = *(const bf16x8*)(hid + swz(lm, bk));
        acc2[0] = MFMA(a, uw[p][0], acc2[0], 0, 0, 0);
        acc2[1] = MFMA(a, uw[p][1], acc2[1], 0, 0, 0);
        if (j < 6) { uw[p][0] = ldW(B3t, j + 2, 0); uw[p][1] = ldW(B3t, j + 2, 1); }
    }

    // PQ weight prologue (in flight over LN)
    bf16x8 pw[2][2], qw[2][2];
    float pqv[2] = { 0.f, 0.f };
    if (Pw1t) {
        #pragma unroll
        for (int s = 0; s < 2; ++s) {
            pw[s][0] = ldW(Pw1t, s, 0); pw[s][1] = ldW(Pw1t, s, 1);
            qw[s][0] = ldW(Pw1b, s, 0); qw[s][1] = ldW(Pw1b, s, 1);
        }
        pqv[0] = pqb1[cA]; pqv[1] = pqb1[cB];
    }

    // v = x + upd + ub2; LN partials
    #pragma unroll
    for (int r = 0; r < 4; ++r) {
        float s = 0.f, qq = 0.f;
        #pragma unroll
        for (int ni = 0; ni < 2; ++ni) {
            float v = acc2[ni][r] + b3v[ni] + res[ni][r];
            acc2[ni][r] = v;
            s += v; qq += v * v;
        }
        #pragma unroll
        for (int off = 1; off < 16; off <<= 1) {
            s += __shfl_xor(s, off);
            qq += __shfl_xor(qq, off);
        }
        if (lm == 0) {
            int row = 4 * q + r;
            sS[w][row] = s; sQ[w][row] = qq;
        }
    }
    LGKMBAR();
    if (tid < 16) {
        float s = 0.f, qq = 0.f;
        #pragma unroll
        for (int i = 0; i < 8; ++i) { s += sS[i][tid]; qq += sQ[i][tid]; }
        float mu = s * (1.0f / HD);
        float var = qq * (1.0f / HD) - mu * mu;
        muv[tid] = mu;
        ivv[tid] = rsqrtf(var + 1e-5f);
    }
    LGKMBAR();
    // LN final + stores + xstage + colsum partials (+ next-layer Q)
    float csum[2] = {0.f, 0.f};
    int tbase = blockIdx.x * 4096 + w * 512;
    #pragma unroll
    for (int r = 0; r < 4; ++r) {
        int row = 4 * q + r;
        int grow = row0 + row;
        float mu = muv[row], iv = ivv[row];
        #pragma unroll
        for (int ni = 0; ni < 2; ++ni) {
            int col = col0 + 16 * ni + lm;
            float o = (acc2[ni][r] - mu) * iv * gv[ni] + bbv[ni];
            *(ushort_t*)(hid + swz(row, col * 2)) = f2bf(o);
            xF[(size_t)grow * HD + col] = o;
            xB[tbase + row * 32 + 16 * ni + lm] = f2bf(o);
            csum[ni] += o;
        }
    }
    if (gsum) {
        #pragma unroll
        for (int ni = 0; ni < 2; ++ni) {
            float s = csum[ni];
            s += __shfl_xor(s, 16);
            s += __shfl_xor(s, 32);
            if (q == 0) atomicAdd(&gsum[col0 + 16 * ni + lm], s);
        }
    }

    // ---- PQ pass ----
    if (Pw1t) {
        LGKMBAR();
        f32x4 aP[2] = {}, aQ[2] = {};
        #pragma unroll
        for (int j = 0; j < 8; ++j) {
            int p = j & 1;
            int bk = (j * 32 + q * 8) * 2;
            bf16x8 a = *(const bf16x8*)(hid + swz(lm, bk));
            aP[0] = MFMA(a, pw[p][0], aP[0], 0, 0, 0);
            aP[1] = MFMA(a, pw[p][1], aP[1], 0, 0, 0);
            aQ[0] = MFMA(a, qw[p][0], aQ[0], 0, 0, 0);
            aQ[1] = MFMA(a, qw[p][1], aQ[1], 0, 0, 0);
            if (j < 6) {
                pw[p][0] = ldW(Pw1t, j + 2, 0); pw[p][1] = ldW(Pw1t, j + 2, 1);
                qw[p][0] = ldW(Pw1b, j + 2, 0); qw[p][1] = ldW(Pw1b, j + 2, 1);
            }
        }
        #pragma unroll
        for (int r = 0; r < 4; ++r) {
            int grow = row0 + 4 * q + r;
            #pragma unroll
            for (int ni = 0; ni < 2; ++ni) {
                int col = col0 + 16 * ni + lm;
                Pout[(size_t)grow * HD + col] = f2bf(aP[ni][r]);
                Qf[(size_t)grow * HD + col] = aQ[ni][r] + pqv[ni];
            }
        }
    }
}

// ---------------- readout ----------------

__global__ __launch_bounds__(256) void readout_mlp(
    const float* __restrict__ gsum,
    const float* __restrict__ w1, const float* __restrict__ b1,
    const float* __restrict__ w2, const float* __restrict__ b2,
    float* __restrict__ out, float invn)
{
    __shared__ float gl[HD], h1[HD];
    int c = threadIdx.x;
    gl[c] = gsum[c] * invn;
    __syncthreads();
    float a = b1[c];
    for (int k = 0; k < HD; ++k) a += gl[k] * w1[k * HD + c];
    h1[c] = fmaxf(a, 0.f);
    __syncthreads();
    float o = b2[c];
    for (int k = 0; k < HD; ++k) o += h1[k] * w2[k * HD + c];
    out[c] = o;
}

// ---------------- orchestration ----------------

extern "C" void kernel_launch(void* const* d_in, const int* in_sizes, int n_in,
                              void* d_out, int out_size, void* d_ws, size_t ws_size,
                              hipStream_t stream) {
    const float* nf    = (const float*)d_in[0];
    const int*   ei    = (const int*)d_in[1];
    const float* ne_w1 = (const float*)d_in[2];
    const float* ne_b1 = (const float*)d_in[3];
    const float* ne_w2 = (const float*)d_in[4];
    const float* ne_b2 = (const float*)d_in[5];
    const float* mw1   = (const float*)d_in[6];
    const float* mb1   = (const float*)d_in[7];
    const float* mw2   = (const float*)d_in[8];
    const float* mb2   = (const float*)d_in[9];
    const float* uw1   = (const float*)d_in[10];
    const float* ub1   = (const float*)d_in[11];
    const float* uw2   = (const float*)d_in[12];
    const float* ub2   = (const float*)d_in[13];
    const float* lng   = (const float*)d_in[14];
    const float* lnb   = (const float*)d_in[15];
    const float* rw1   = (const float*)d_in[16];
    const float* rb1   = (const float*)d_in[17];
    const float* rw2   = (const float*)d_in[18];
    const float* rb2   = (const float*)d_in[19];

    const int* e_src = ei;
    const int* e_dst = ei + NE;

    char* w = (char*)d_ws;
    size_t off = 0;
    auto alloc = [&](size_t bytes) -> void* {
        void* p = w + off;
        off = (off + bytes + 255) & ~(size_t)255;
        return p;
    };
    const size_t NF32 = (size_t)NN * HD * sizeof(float);
    const size_t NF16 = (size_t)NN * HD * sizeof(ushort_t);
    const size_t WM16 = (size_t)HD * HD * sizeof(ushort_t);

    float* x    = (float*)alloc(NF32);
    float* Qf   = (float*)alloc(NF32);
    float* gsum = (float*)alloc(HD * sizeof(float));
    float* degf = (float*)alloc(NN * sizeof(float));
    float* b2u1 = (float*)alloc(NL * HD * sizeof(float));

    ushort_t* nfT   = (ushort_t*)alloc(NF16);
    ushort_t* xb    = (ushort_t*)alloc(NF16);
    ushort_t* PbA   = (ushort_t*)alloc(NF16);
    ushort_t* PbB   = (ushort_t*)alloc(NF16);
    ushort_t* neT1  = (ushort_t*)alloc(WM16);
    ushort_t* neT2  = (ushort_t*)alloc(WM16);
    ushort_t* w1tT  = (ushort_t*)alloc(NL * WM16);
    ushort_t* w1bT  = (ushort_t*)alloc(NL * WM16);
    ushort_t* u1tT  = (ushort_t*)alloc(NL * WM16);
    ushort_t* u1bT  = (ushort_t*)alloc(NL * WM16);
    ushort_t* u2T   = (ushort_t*)alloc(NL * WM16);
    ushort_t* w2uT  = (ushort_t*)alloc(NL * WM16);
    ushort_t* w2rmb = (ushort_t*)alloc(NL * WM16);

    int* deg       = (int*)alloc(NN * sizeof(int));
    int* row_start = (int*)alloc((NN + 1) * sizeof(int));
    int* cursor    = (int*)alloc(NN * sizeof(int));
    int* srcs      = (int*)alloc(NE * sizeof(int));

    hipMemsetAsync(deg, 0, NN * sizeof(int), stream);

    // CSR build
    hist_deg<<<(NE + 255) / 256, 256, 0, stream>>>(e_dst, deg, NE);
    scan_csr<<<1, 1024, 0, stream>>>(deg, row_start, cursor, degf, gsum, NN);
    scatter_src<<<(NE + 255) / 256, 256, 0, stream>>>(e_src, e_dst, cursor, srcs, NE);

    // weight prep
    TArgs ta;
    ta.d[0] = { ne_w1, neT1, 2 };
    ta.d[1] = { ne_w2, neT2, 2 };
    for (int l = 0; l < NL; ++l) {
        const float* w1l = mw1 + (size_t)l * 2 * HD * HD;
        const float* u1l = uw1 + (size_t)l * 2 * HD * HD;
        ta.d[2 + l]  = { w1l,                       w1tT + (size_t)l * HD * HD, 2 };
        ta.d[5 + l]  = { w1l + (size_t)HD * HD,     w1bT + (size_t)l * HD * HD, 2 };
        ta.d[8 + l]  = { u1l,                       u1tT + (size_t)l * HD * HD, 2 };
        ta.d[11 + l] = { u1l + (size_t)HD * HD,     u1bT + (size_t)l * HD * HD, 1 };
        ta.d[14 + l] = { uw2 + (size_t)l * HD * HD, u2T + (size_t)l * HD * HD, 2 };
        ta.d[17 + l] = { mw2 + (size_t)l * HD * HD, w2rmb + (size_t)l * HD * HD, 0 };
    }
    conv_t<<<dim3(16, 20), 256, 0, stream>>>(ta);
    cast_nf_tiled<<<NN / 16, 256, 0, stream>>>(nf, nfT);
    bias_compose<<<NL, 256, 0, stream>>>(mb2, uw1, b2u1);
    gemm_w2u<<<dim3(4, 4, NL), 256, 0, stream>>>(u1bT, w2rmb, w2uT);

    // encoder + layer-0 P/Q
    enc_pq<<<NN / 16, 512, 0, stream>>>(nfT, neT1, neT2, ne_b1, ne_b2,
                                        w1tT, w1bT, mb1, x, xb, PbA, Qf, NN);

    const ushort_t* pin = PbA;
    ushort_t* pout = PbB;
    for (int l = 0; l < NL; ++l) {
        int nl = l + 1;
        const ushort_t* pw1t = (nl < NL) ? w1tT + (size_t)nl * HD * HD : nullptr;
        const ushort_t* pw1b = (nl < NL) ? w1bT + (size_t)nl * HD * HD : nullptr;
        const float*    pqb1 = (nl < NL) ? mb1 + (size_t)nl * HD : nullptr;
        float* gs = (l == NL - 1) ? gsum : nullptr;
        upd_ln<<<NN / 16, 512, 0, stream>>>(
            xb, pin, Qf, row_start, srcs,
            u1tT + (size_t)l * HD * HD, w2uT + (size_t)l * HD * HD,
            u2T + (size_t)l * HD * HD, degf,
            ub1 + (size_t)l * HD, b2u1 + (size_t)l * HD, ub2 + (size_t)l * HD,
            lng + (size_t)l * HD, lnb + (size_t)l * HD,
            pw1t, pw1b, pqb1, gs, x, xb, pout, NN);
        const ushort_t* tmp = pin; pin = pout; pout = (ushort_t*)tmp;
    }

    // readout
    readout_mlp<<<1, 256, 0, stream>>>(gsum, rw1, rb1, rw2, rb2, (float*)d_out, 1.0f / NN);
}

// Round 15
// 283.761 us; speedup vs baseline: 1.1065x; 1.1065x over previous
//
#include <hip/hip_runtime.h>

#define NN 10000
#define NE 320000
#define HD 256
#define NL 3

typedef unsigned short ushort_t;
typedef __attribute__((ext_vector_type(8))) short bf16x8;
typedef __attribute__((ext_vector_type(4))) float f32x4;

#define MFMA __builtin_amdgcn_mfma_f32_16x16x32_bf16

#define WAITV(N) asm volatile("s_waitcnt vmcnt(" #N ")" ::: "memory")
#define SCHEDPIN() __builtin_amdgcn_sched_barrier(0)
#define LGKMBAR() do { asm volatile("s_waitcnt lgkmcnt(0)" ::: "memory"); \
                       __builtin_amdgcn_s_barrier(); __builtin_amdgcn_sched_barrier(0); } while (0)

__device__ __forceinline__ unsigned short f2bf(float x) {
    unsigned u = __float_as_uint(x);
    unsigned rounding = 0x7FFFu + ((u >> 16) & 1u);
    return (unsigned short)((u + rounding) >> 16);
}
__device__ __forceinline__ float bf2f(unsigned short u) {
    return __uint_as_float(((unsigned)u) << 16);
}
__device__ __forceinline__ int sw2(int col) { return (col & 3) ^ ((col >> 2) & 3); }
__device__ __forceinline__ void dma16(const void* g, void* l) {
    __builtin_amdgcn_global_load_lds(
        (const __attribute__((address_space(1))) unsigned int*)g,
        (__attribute__((address_space(3))) unsigned int*)l, 16, 0, 0);
}

// ---------------- CSR build ----------------

__global__ void hist_deg(const int* __restrict__ dst, int* __restrict__ deg, int E) {
    int e = blockIdx.x * blockDim.x + threadIdx.x;
    if (e < E) atomicAdd(&deg[dst[e]], 1);
}

__global__ __launch_bounds__(1024) void scan_csr(const int* __restrict__ deg,
                                                 int* __restrict__ row_start,
                                                 int* __restrict__ cursor,
                                                 float* __restrict__ degf,
                                                 float* __restrict__ gsum, int n) {
    __shared__ int wsum[16];
    __shared__ int carry_s;
    int tid = threadIdx.x, lane = tid & 63, wid = tid >> 6;
    if (tid < HD) gsum[tid] = 0.f;
    if (tid == 0) carry_s = 0;
    __syncthreads();
    for (int base = 0; base < n; base += 1024) {
        int i = base + tid;
        int v = (i < n) ? deg[i] : 0;
        int s = v;
        #pragma unroll
        for (int off = 1; off < 64; off <<= 1) {
            int t = __shfl_up(s, off);
            if (lane >= off) s += t;
        }
        if (lane == 63) wsum[wid] = s;
        __syncthreads();
        if (wid == 0 && lane < 16) {
            int ws = wsum[lane];
            #pragma unroll
            for (int off = 1; off < 16; off <<= 1) {
                int t = __shfl_up(ws, off);
                if (lane >= off) ws += t;
            }
            wsum[lane] = ws;
        }
        __syncthreads();
        int carry = carry_s;
        int wpre = (wid > 0) ? wsum[wid - 1] : 0;
        int incl = carry + wpre + s;
        int excl = incl - v;
        if (i < n) { row_start[i] = excl; cursor[i] = excl; degf[i] = (float)v; }
        __syncthreads();
        if (tid == 1023) carry_s = incl;
        __syncthreads();
    }
    if (tid == 0) row_start[n] = carry_s;
}

__global__ void scatter_src(const int* __restrict__ src, const int* __restrict__ dst,
                            int* __restrict__ cursor, int* __restrict__ src_sorted, int E) {
    int e = blockIdx.x * blockDim.x + threadIdx.x;
    if (e < E) {
        int pos = atomicAdd(&cursor[dst[e]], 1);
        src_sorted[pos] = src[e];
    }
}

// ---------------- weight prep ----------------
// mode 0: straight cast (row-major bf16)
// mode 1: transpose cast (row-major bf16 of src^T)
// mode 2: transpose + K-sliced tile for DMA: ushort idx (k,col) =
//         (k>>5)*8192 + col*32 + (((k>>3)&3) ^ sw2(col))*8 + (k&7)

struct TDesc { const float* src; ushort_t* dst; int mode; };
struct TArgs { TDesc d[20]; };

__global__ __launch_bounds__(256) void conv_t(TArgs args) {
    __shared__ ushort_t tile[64][65];
    const float* src = args.d[blockIdx.y].src;
    ushort_t* dst = args.d[blockIdx.y].dst;
    int mode = args.d[blockIdx.y].mode;
    int t = blockIdx.x;
    int r0 = (t >> 2) * 64, c0 = (t & 3) * 64;
    int tid = threadIdx.x;
    int rr = tid >> 4, cc4 = (tid & 15) * 4;
    if (mode == 0) {
        #pragma unroll
        for (int i = 0; i < 4; ++i) {
            int r = r0 + rr + i * 16;
            float4 v = *(const float4*)(src + (size_t)r * HD + c0 + cc4);
            ushort4 o = { f2bf(v.x), f2bf(v.y), f2bf(v.z), f2bf(v.w) };
            *(ushort4*)(dst + (size_t)r * HD + c0 + cc4) = o;
        }
        return;
    }
    #pragma unroll
    for (int i = 0; i < 4; ++i) {
        int r = rr + i * 16;
        float4 v = *(const float4*)(src + (size_t)(r0 + r) * HD + c0 + cc4);
        tile[cc4 + 0][r] = f2bf(v.x);
        tile[cc4 + 1][r] = f2bf(v.y);
        tile[cc4 + 2][r] = f2bf(v.z);
        tile[cc4 + 3][r] = f2bf(v.w);
    }
    __syncthreads();
    #pragma unroll
    for (int i = 0; i < 4; ++i) {
        int c = rr + i * 16;
        ushort4 o = { tile[c][cc4], tile[c][cc4 + 1], tile[c][cc4 + 2], tile[c][cc4 + 3] };
        if (mode == 1) {
            *(ushort4*)(dst + (size_t)(c0 + c) * HD + r0 + cc4) = o;
        } else {
            int col = c0 + c;
            int k = r0 + cc4;
            int s = k >> 5, qv = (k >> 3) & 3;
            int slot = qv ^ sw2(col);
            *(ushort4*)(dst + (size_t)s * 8192 + col * 32 + slot * 8 + (k & 7)) = o;
        }
    }
}

// nf -> bf16 A-tiles: idx = blk*4096 + (col>>5)*512 + row*32 + (col&31)
__global__ __launch_bounds__(256) void cast_nf_tiled(const float* __restrict__ src,
                                                     ushort_t* __restrict__ dst) {
    int blk = blockIdx.x;
    int row = threadIdx.x >> 4, g = threadIdx.x & 15;
    const float* sp = src + ((size_t)blk * 16 + row) * HD + g * 16;
    ushort_t* dp = dst + (size_t)blk * 4096 + (g >> 1) * 512 + row * 32 + (g & 1) * 16;
    #pragma unroll
    for (int j = 0; j < 4; ++j) {
        float4 v = *(const float4*)(sp + j * 4);
        ushort4 o = { f2bf(v.x), f2bf(v.y), f2bf(v.z), f2bf(v.w) };
        *(ushort4*)(dp + j * 4) = o;
    }
}

__global__ __launch_bounds__(256) void bias_compose(const float* __restrict__ mb2,
                                                    const float* __restrict__ uw1,
                                                    float* __restrict__ out) {
    int l = blockIdx.x, c = threadIdx.x;
    const float* b2l = mb2 + (size_t)l * HD;
    const float* u1b = uw1 + (size_t)l * 2 * HD * HD + (size_t)HD * HD;
    float s = 0.f;
    for (int k = 0; k < HD; ++k) s += b2l[k] * u1b[(size_t)k * HD + c];
    out[(size_t)l * HD + c] = s;
}

// w2uT[l] = (w2[l]@u1b[l])^T, written in tiled layout (first idx n, second k)
__global__ __launch_bounds__(256) void gemm_w2u(
    const ushort_t* __restrict__ Abase, const ushort_t* __restrict__ Btbase,
    ushort_t* __restrict__ outBase)
{
    const ushort_t* A  = Abase  + (size_t)blockIdx.z * HD * HD;
    const ushort_t* Bt = Btbase + (size_t)blockIdx.z * HD * HD;
    ushort_t* outB     = outBase + (size_t)blockIdx.z * HD * HD;
    int tid = threadIdx.x;
    int wid = tid >> 6, lane = tid & 63;
    int wm = wid >> 1, wn = wid & 1;
    int row0 = blockIdx.x * 64 + wm * 32;
    int col0 = blockIdx.y * 64 + wn * 32;
    int lm = lane & 15, lk = (lane >> 4) * 8;
    f32x4 acc[2][2] = {};
    const ushort_t* a0p = A + (size_t)(row0 + lm) * HD + lk;
    const ushort_t* a1p = A + (size_t)(row0 + 16 + lm) * HD + lk;
    const ushort_t* b0p = Bt + (size_t)(col0 + lm) * HD + lk;
    const ushort_t* b1p = Bt + (size_t)(col0 + 16 + lm) * HD + lk;
    #pragma unroll
    for (int k0 = 0; k0 < HD; k0 += 32) {
        bf16x8 a0 = *(const bf16x8*)(a0p + k0);
        bf16x8 a1 = *(const bf16x8*)(a1p + k0);
        bf16x8 b0 = *(const bf16x8*)(b0p + k0);
        bf16x8 b1 = *(const bf16x8*)(b1p + k0);
        acc[0][0] = MFMA(a0, b0, acc[0][0], 0, 0, 0);
        acc[0][1] = MFMA(a0, b1, acc[0][1], 0, 0, 0);
        acc[1][0] = MFMA(a1, b0, acc[1][0], 0, 0, 0);
        acc[1][1] = MFMA(a1, b1, acc[1][1], 0, 0, 0);
    }
    int orow = (lane >> 4) * 4;
    #pragma unroll
    for (int mi = 0; mi < 2; ++mi)
        #pragma unroll
        for (int r = 0; r < 4; ++r) {
            int row = row0 + mi * 16 + orow + r;        // n
            #pragma unroll
            for (int ni = 0; ni < 2; ++ni) {
                int col = col0 + ni * 16 + lm;          // k
                int s = col >> 5, qv = (col >> 3) & 3;
                int slot = qv ^ sw2(row);
                outB[(size_t)s * 8192 + row * 32 + slot * 8 + (col & 7)] = f2bf(acc[mi][ni][r]);
            }
        }
}

// ---------------- LDS swizzle for hid [16 rows][512B] ----------------
__device__ __forceinline__ int swz(int row, int byte_in_row) {
    return row * 512 + (byte_in_row ^ ((row & 7) << 4));
}

// ---------------- fused encoder + layer-0 P/Q (tiled operands, contiguous DMA) ----------------

__global__ __launch_bounds__(512, 4) void enc_pq(
    const ushort_t* __restrict__ Anf, const ushort_t* __restrict__ B1t,
    const ushort_t* __restrict__ B2t,
    const float* __restrict__ b1, const float* __restrict__ b2,
    const ushort_t* __restrict__ Pw1t, const ushort_t* __restrict__ Pw1b,
    const float* __restrict__ pqb1,
    float* __restrict__ xF, ushort_t* __restrict__ xB,
    ushort_t* __restrict__ P, float* __restrict__ Q, int M)
{
    __shared__ char wlds[8][2][2][2048];
    __shared__ char hid[16 * 512];
    int tid = threadIdx.x;
    int w = tid >> 6, lane = tid & 63;
    int lm = lane & 15, q = lane >> 4;
    int row0 = blockIdx.x * 16;
    int col0 = w * 32;
    int cA = col0 + lm, cB = col0 + 16 + lm;

    auto stageW = [&](const ushort_t* Wt, int s, int p, int m) {
        #pragma unroll
        for (int i = 0; i < 2; ++i)
            dma16((const char*)Wt + (size_t)s * 16384 + (col0 + 16 * i) * 64 + lane * 16,
                  wlds[w][p][m] + i * 1024);
    };
    auto readB = [&](int p, int m, int ni) -> bf16x8 {
        int col = col0 + 16 * ni + lm;
        int q2 = q ^ sw2(col);
        return *(const bf16x8*)(wlds[w][p][m] + ni * 1024 + lm * 64 + q2 * 16);
    };

    float b1v[2] = { b1[cA], b1[cB] };
    float b2v[2] = { b2[cA], b2[cB] };
    float pqv[2] = { pqb1[cA], pqb1[cB] };

    const ushort_t* ap = Anf + (size_t)blockIdx.x * 4096 + lm * 32 + q * 8;
    bf16x8 ax[2];
    #pragma unroll
    for (int s = 0; s < 2; ++s) {
        stageW(B1t, s, s, 0);
        ax[s] = *(const bf16x8*)(ap + s * 512);
        SCHEDPIN();
    }

    // ---- pass 1: acc = nf @ W1 ----
    f32x4 acc[2] = {};
    #pragma unroll
    for (int j = 0; j < 8; ++j) {
        int p = j & 1;
        if (j < 7) { WAITV(3); } else { WAITV(0); }
        acc[0] = MFMA(ax[p], readB(p, 0, 0), acc[0], 0, 0, 0);
        acc[1] = MFMA(ax[p], readB(p, 0, 1), acc[1], 0, 0, 0);
        SCHEDPIN();
        if (j < 6) {
            stageW(B1t, j + 2, p, 0);
            ax[p] = *(const bf16x8*)(ap + (j + 2) * 512);
            SCHEDPIN();
        }
    }

    #pragma unroll
    for (int s = 0; s < 2; ++s) { stageW(B2t, s, s, 0); SCHEDPIN(); }
    #pragma unroll
    for (int ni = 0; ni < 2; ++ni) {
        int col = col0 + 16 * ni + lm;
        #pragma unroll
        for (int r = 0; r < 4; ++r) {
            int row = 4 * q + r;
            float v = fmaxf(acc[ni][r] + b1v[ni], 0.f);
            *(ushort_t*)(hid + swz(row, col * 2)) = f2bf(v);
        }
    }
    LGKMBAR();

    // ---- pass 2: acc2 = hid @ W2 ----
    f32x4 acc2[2] = {};
    #pragma unroll
    for (int j = 0; j < 8; ++j) {
        int p = j & 1;
        if (j < 7) { WAITV(2); } else { WAITV(0); }
        int bk = (j * 32 + q * 8) * 2;
        bf16x8 a = *(const bf16x8*)(hid + swz(lm, bk));
        acc2[0] = MFMA(a, readB(p, 0, 0), acc2[0], 0, 0, 0);
        acc2[1] = MFMA(a, readB(p, 0, 1), acc2[1], 0, 0, 0);
        SCHEDPIN();
        if (j < 6) { stageW(B2t, j + 2, p, 0); SCHEDPIN(); }
    }

    // PQ prologue; xstage after all pass-2 hid reads
    #pragma unroll
    for (int s = 0; s < 2; ++s) {
        stageW(Pw1t, s, s, 0);
        stageW(Pw1b, s, s, 1);
        SCHEDPIN();
    }
    LGKMBAR();
    int tbase = blockIdx.x * 4096 + w * 512;
    #pragma unroll
    for (int ni = 0; ni < 2; ++ni) {
        int col = col0 + 16 * ni + lm;
        #pragma unroll
        for (int r = 0; r < 4; ++r) {
            int row = 4 * q + r;
            int grow = row0 + row;
            float v = acc2[ni][r] + b2v[ni];
            *(ushort_t*)(hid + swz(row, col * 2)) = f2bf(v);
            xF[(size_t)grow * HD + col] = v;
            xB[tbase + row * 32 + 16 * ni + lm] = f2bf(v);
        }
    }
    LGKMBAR();

    // ---- PQ pass ----
    f32x4 aP[2] = {}, aQ[2] = {};
    #pragma unroll
    for (int j = 0; j < 8; ++j) {
        int p = j & 1;
        if (j < 7) { WAITV(4); } else { WAITV(0); }
        int bk = (j * 32 + q * 8) * 2;
        bf16x8 a = *(const bf16x8*)(hid + swz(lm, bk));
        #pragma unroll
        for (int ni = 0; ni < 2; ++ni) {
            aP[ni] = MFMA(a, readB(p, 0, ni), aP[ni], 0, 0, 0);
            aQ[ni] = MFMA(a, readB(p, 1, ni), aQ[ni], 0, 0, 0);
        }
        SCHEDPIN();
        if (j < 6) {
            stageW(Pw1t, j + 2, p, 0);
            stageW(Pw1b, j + 2, p, 1);
            SCHEDPIN();
        }
    }
    #pragma unroll
    for (int r = 0; r < 4; ++r) {
        int grow = row0 + 4 * q + r;
        #pragma unroll
        for (int ni = 0; ni < 2; ++ni) {
            int col = col0 + 16 * ni + lm;
            P[(size_t)grow * HD + col] = f2bf(aP[ni][r]);
            Q[(size_t)grow * HD + col] = aQ[ni][r] + pqv[ni];
        }
    }
}

// ---------------- edge aggregation (2 nodes/wave, interleaved streams) ----------------

__global__ __launch_bounds__(256) void edge_agg(
    const ushort_t* __restrict__ Pb, const float* __restrict__ Qf,
    const int* __restrict__ row_start, const int* __restrict__ srcs,
    ushort_t* __restrict__ HaggT)
{
    int wv = blockIdx.x * 4 + (threadIdx.x >> 6);
    int lane = threadIdx.x & 63;
    int c4 = lane * 4;
    int n0 = wv * 2, n1 = n0 + 1;
    float4 qb0 = *(const float4*)(Qf + (size_t)n0 * HD + c4);
    float4 qb1 = *(const float4*)(Qf + (size_t)n1 * HD + c4);
    float4 A0 = {0.f, 0.f, 0.f, 0.f}, A1 = {0.f, 0.f, 0.f, 0.f};
    int j0 = row_start[n0], e0 = row_start[n0 + 1];
    int j1 = row_start[n1], e1 = row_start[n1 + 1];
    // interleaved phase: 4+4 loads in flight from two independent streams
    while (j0 + 4 <= e0 && j1 + 4 <= e1) {
        ushort4 p[8];
        #pragma unroll
        for (int u = 0; u < 4; ++u)
            p[u] = *(const ushort4*)(Pb + (size_t)srcs[j0 + u] * HD + c4);
        #pragma unroll
        for (int u = 0; u < 4; ++u)
            p[4 + u] = *(const ushort4*)(Pb + (size_t)srcs[j1 + u] * HD + c4);
        #pragma unroll
        for (int u = 0; u < 4; ++u) {
            A0.x += fmaxf(bf2f(p[u].x) + qb0.x, 0.f);
            A0.y += fmaxf(bf2f(p[u].y) + qb0.y, 0.f);
            A0.z += fmaxf(bf2f(p[u].z) + qb0.z, 0.f);
            A0.w += fmaxf(bf2f(p[u].w) + qb0.w, 0.f);
            A1.x += fmaxf(bf2f(p[4 + u].x) + qb1.x, 0.f);
            A1.y += fmaxf(bf2f(p[4 + u].y) + qb1.y, 0.f);
            A1.z += fmaxf(bf2f(p[4 + u].z) + qb1.z, 0.f);
            A1.w += fmaxf(bf2f(p[4 + u].w) + qb1.w, 0.f);
        }
        j0 += 4; j1 += 4;
    }
    // drain stream 0
    for (; j0 + 4 <= e0; j0 += 4) {
        ushort4 p[4];
        #pragma unroll
        for (int u = 0; u < 4; ++u)
            p[u] = *(const ushort4*)(Pb + (size_t)srcs[j0 + u] * HD + c4);
        #pragma unroll
        for (int u = 0; u < 4; ++u) {
            A0.x += fmaxf(bf2f(p[u].x) + qb0.x, 0.f);
            A0.y += fmaxf(bf2f(p[u].y) + qb0.y, 0.f);
            A0.z += fmaxf(bf2f(p[u].z) + qb0.z, 0.f);
            A0.w += fmaxf(bf2f(p[u].w) + qb0.w, 0.f);
        }
    }
    for (; j0 < e0; ++j0) {
        ushort4 p0 = *(const ushort4*)(Pb + (size_t)srcs[j0] * HD + c4);
        A0.x += fmaxf(bf2f(p0.x) + qb0.x, 0.f);
        A0.y += fmaxf(bf2f(p0.y) + qb0.y, 0.f);
        A0.z += fmaxf(bf2f(p0.z) + qb0.z, 0.f);
        A0.w += fmaxf(bf2f(p0.w) + qb0.w, 0.f);
    }
    // drain stream 1
    for (; j1 + 4 <= e1; j1 += 4) {
        ushort4 p[4];
        #pragma unroll
        for (int u = 0; u < 4; ++u)
            p[u] = *(const ushort4*)(Pb + (size_t)srcs[j1 + u] * HD + c4);
        #pragma unroll
        for (int u = 0; u < 4; ++u) {
            A1.x += fmaxf(bf2f(p[u].x) + qb1.x, 0.f);
            A1.y += fmaxf(bf2f(p[u].y) + qb1.y, 0.f);
            A1.z += fmaxf(bf2f(p[u].z) + qb1.z, 0.f);
            A1.w += fmaxf(bf2f(p[u].w) + qb1.w, 0.f);
        }
    }
    for (; j1 < e1; ++j1) {
        ushort4 p0 = *(const ushort4*)(Pb + (size_t)srcs[j1] * HD + c4);
        A1.x += fmaxf(bf2f(p0.x) + qb1.x, 0.f);
        A1.y += fmaxf(bf2f(p0.y) + qb1.y, 0.f);
        A1.z += fmaxf(bf2f(p0.z) + qb1.z, 0.f);
        A1.w += fmaxf(bf2f(p0.w) + qb1.w, 0.f);
    }
    ushort4 o0 = { f2bf(A0.x), f2bf(A0.y), f2bf(A0.z), f2bf(A0.w) };
    ushort4 o1 = { f2bf(A1.x), f2bf(A1.y), f2bf(A1.z), f2bf(A1.w) };
    int t0 = (n0 >> 4) * 4096 + (c4 >> 5) * 512 + (n0 & 15) * 32 + (c4 & 31);
    int t1 = (n1 >> 4) * 4096 + (c4 >> 5) * 512 + (n1 & 15) * 32 + (c4 & 31);
    *(ushort4*)(HaggT + t0) = o0;
    *(ushort4*)(HaggT + t1) = o1;
}

// ---------------- fused update + LN + next P/Q (tiled operands, contiguous DMA) ----------------

__global__ __launch_bounds__(512, 4) void upd_ln(
    const ushort_t* __restrict__ xb, const ushort_t* __restrict__ Hb,
    const ushort_t* __restrict__ B1t, const ushort_t* __restrict__ B2t,
    const ushort_t* __restrict__ B3t,
    const float* __restrict__ degf,
    const float* __restrict__ b1, const float* __restrict__ bias2,
    const float* __restrict__ b3,
    const float* __restrict__ g, const float* __restrict__ bb,
    const ushort_t* __restrict__ Pw1t, const ushort_t* __restrict__ Pw1b,
    const float* __restrict__ pqb1,
    float* __restrict__ gsum,
    float* __restrict__ xF, ushort_t* __restrict__ xB,
    ushort_t* __restrict__ P, float* __restrict__ Q, int M)
{
    __shared__ char wlds[8][2][2][2048];
    __shared__ char hid[16 * 512];
    __shared__ float sS[8][16], sQ[8][16], muv[16], ivv[16];

    int tid = threadIdx.x;
    int w = tid >> 6, lane = tid & 63;
    int lm = lane & 15, q = lane >> 4;
    int row0 = blockIdx.x * 16;
    int col0 = w * 32;
    int cA = col0 + lm, cB = col0 + 16 + lm;

    auto stageW = [&](const ushort_t* Wt, int s, int p, int m) {
        #pragma unroll
        for (int i = 0; i < 2; ++i)
            dma16((const char*)Wt + (size_t)s * 16384 + (col0 + 16 * i) * 64 + lane * 16,
                  wlds[w][p][m] + i * 1024);
    };
    auto readB = [&](int p, int m, int ni) -> bf16x8 {
        int col = col0 + 16 * ni + lm;
        int q2 = q ^ sw2(col);
        return *(const bf16x8*)(wlds[w][p][m] + ni * 1024 + lm * 64 + q2 * 16);
    };

    const ushort_t* xp = xb + (size_t)blockIdx.x * 4096 + lm * 32 + q * 8;
    const ushort_t* hp = Hb + (size_t)blockIdx.x * 4096 + lm * 32 + q * 8;
    bf16x8 ax[2], ah[2];
    #pragma unroll
    for (int s = 0; s < 2; ++s) {
        stageW(B1t, s, s, 0);
        stageW(B2t, s, s, 1);
        ax[s] = *(const bf16x8*)(xp + s * 512);
        ah[s] = *(const bf16x8*)(hp + s * 512);
        SCHEDPIN();
    }

    float b1v[2] = { b1[cA], b1[cB] };
    float bzv[2] = { bias2[cA], bias2[cB] };
    float b3v[2] = { b3[cA], b3[cB] };
    float gv[2]  = { g[cA],  g[cB]  };
    float bbv[2] = { bb[cA], bb[cB] };
    float pqv[2] = { Pw1t ? pqb1[cA] : 0.f, Pw1t ? pqb1[cB] : 0.f };
    float dgv[4], res[2][4];
    #pragma unroll
    for (int r = 0; r < 4; ++r) {
        int row = 4 * q + r;
        dgv[r] = degf[row0 + row];
        res[0][r] = xF[(size_t)(row0 + row) * HD + cA];
        res[1][r] = xF[(size_t)(row0 + row) * HD + cB];
    }

    // ---- pass 1+2: acc = x@u1t + Hagg@w2u ----
    f32x4 acc[2] = {};
    #pragma unroll
    for (int j = 0; j < 8; ++j) {
        int p = j & 1;
        if (j < 7) { WAITV(6); } else { WAITV(0); }
        #pragma unroll
        for (int ni = 0; ni < 2; ++ni) {
            acc[ni] = MFMA(ax[p], readB(p, 0, ni), acc[ni], 0, 0, 0);
            acc[ni] = MFMA(ah[p], readB(p, 1, ni), acc[ni], 0, 0, 0);
        }
        SCHEDPIN();
        if (j < 6) {
            stageW(B1t, j + 2, p, 0);
            stageW(B2t, j + 2, p, 1);
            ax[p] = *(const bf16x8*)(xp + (j + 2) * 512);
            ah[p] = *(const bf16x8*)(hp + (j + 2) * 512);
            SCHEDPIN();
        }
    }

    // transition: u2 prologue over hid build
    #pragma unroll
    for (int s = 0; s < 2; ++s) { stageW(B3t, s, s, 0); SCHEDPIN(); }
    #pragma unroll
    for (int r = 0; r < 4; ++r) {
        int row = 4 * q + r;
        #pragma unroll
        for (int ni = 0; ni < 2; ++ni) {
            int col = col0 + 16 * ni + lm;
            float v = fmaxf(acc[ni][r] + b1v[ni] + dgv[r] * bzv[ni], 0.f);
            *(ushort_t*)(hid + swz(row, col * 2)) = f2bf(v);
        }
    }
    LGKMBAR();

    // ---- pass 3: upd = hid @ u2 ----
    f32x4 acc2[2] = {};
    #pragma unroll
    for (int j = 0; j < 8; ++j) {
        int p = j & 1;
        if (j < 7) { WAITV(2); } else { WAITV(0); }
        int bk = (j * 32 + q * 8) * 2;
        bf16x8 a = *(const bf16x8*)(hid + swz(lm, bk));
        acc2[0] = MFMA(a, readB(p, 0, 0), acc2[0], 0, 0, 0);
        acc2[1] = MFMA(a, readB(p, 0, 1), acc2[1], 0, 0, 0);
        SCHEDPIN();
        if (j < 6) { stageW(B3t, j + 2, p, 0); SCHEDPIN(); }
    }

    // PQ prologue over LN
    if (Pw1t) {
        #pragma unroll
        for (int s = 0; s < 2; ++s) {
            stageW(Pw1t, s, s, 0);
            stageW(Pw1b, s, s, 1);
            SCHEDPIN();
        }
    }
    // v = x + upd + ub2; LN partials
    #pragma unroll
    for (int r = 0; r < 4; ++r) {
        float s = 0.f, qq = 0.f;
        #pragma unroll
        for (int ni = 0; ni < 2; ++ni) {
            float v = acc2[ni][r] + b3v[ni] + res[ni][r];
            acc2[ni][r] = v;
            s += v; qq += v * v;
        }
        #pragma unroll
        for (int off = 1; off < 16; off <<= 1) {
            s += __shfl_xor(s, off);
            qq += __shfl_xor(qq, off);
        }
        if (lm == 0) {
            int row = 4 * q + r;
            sS[w][row] = s; sQ[w][row] = qq;
        }
    }
    LGKMBAR();
    if (tid < 16) {
        float s = 0.f, qq = 0.f;
        #pragma unroll
        for (int i = 0; i < 8; ++i) { s += sS[i][tid]; qq += sQ[i][tid]; }
        float mu = s * (1.0f / HD);
        float var = qq * (1.0f / HD) - mu * mu;
        muv[tid] = mu;
        ivv[tid] = rsqrtf(var + 1e-5f);
    }
    LGKMBAR();
    // LN final + stores + xstage + colsum partials
    float csum[2] = {0.f, 0.f};
    int tbase = blockIdx.x * 4096 + w * 512;
    #pragma unroll
    for (int r = 0; r < 4; ++r) {
        int row = 4 * q + r;
        int grow = row0 + row;
        float mu = muv[row], iv = ivv[row];
        #pragma unroll
        for (int ni = 0; ni < 2; ++ni) {
            int col = col0 + 16 * ni + lm;
            float o = (acc2[ni][r] - mu) * iv * gv[ni] + bbv[ni];
            *(ushort_t*)(hid + swz(row, col * 2)) = f2bf(o);
            xF[(size_t)grow * HD + col] = o;
            xB[tbase + row * 32 + 16 * ni + lm] = f2bf(o);
            csum[ni] += o;
        }
    }
    if (gsum) {
        #pragma unroll
        for (int ni = 0; ni < 2; ++ni) {
            float s = csum[ni];
            s += __shfl_xor(s, 16);
            s += __shfl_xor(s, 32);
            if (q == 0) atomicAdd(&gsum[col0 + 16 * ni + lm], s);
        }
    }

    // ---- PQ pass ----
    if (Pw1t) {
        LGKMBAR();
        f32x4 aP[2] = {}, aQ[2] = {};
        #pragma unroll
        for (int j = 0; j < 8; ++j) {
            int p = j & 1;
            if (j < 7) { WAITV(4); } else { WAITV(0); }
            int bk = (j * 32 + q * 8) * 2;
            bf16x8 a = *(const bf16x8*)(hid + swz(lm, bk));
            #pragma unroll
            for (int ni = 0; ni < 2; ++ni) {
                aP[ni] = MFMA(a, readB(p, 0, ni), aP[ni], 0, 0, 0);
                aQ[ni] = MFMA(a, readB(p, 1, ni), aQ[ni], 0, 0, 0);
            }
            SCHEDPIN();
            if (j < 6) {
                stageW(Pw1t, j + 2, p, 0);
                stageW(Pw1b, j + 2, p, 1);
                SCHEDPIN();
            }
        }
        #pragma unroll
        for (int r = 0; r < 4; ++r) {
            int grow = row0 + 4 * q + r;
            #pragma unroll
            for (int ni = 0; ni < 2; ++ni) {
                int col = col0 + 16 * ni + lm;
                P[(size_t)grow * HD + col] = f2bf(aP[ni][r]);
                Q[(size_t)grow * HD + col] = aQ[ni][r] + pqv[ni];
            }
        }
    }
}

// ---------------- readout ----------------

__global__ __launch_bounds__(256) void readout_mlp(
    const float* __restrict__ gsum,
    const float* __restrict__ w1, const float* __restrict__ b1,
    const float* __restrict__ w2, const float* __restrict__ b2,
    float* __restrict__ out, float invn)
{
    __shared__ float gl[HD], h1[HD];
    int c = threadIdx.x;
    gl[c] = gsum[c] * invn;
    __syncthreads();
    float a = b1[c];
    for (int k = 0; k < HD; ++k) a += gl[k] * w1[k * HD + c];
    h1[c] = fmaxf(a, 0.f);
    __syncthreads();
    float o = b2[c];
    for (int k = 0; k < HD; ++k) o += h1[k] * w2[k * HD + c];
    out[c] = o;
}

// ---------------- orchestration ----------------

extern "C" void kernel_launch(void* const* d_in, const int* in_sizes, int n_in,
                              void* d_out, int out_size, void* d_ws, size_t ws_size,
                              hipStream_t stream) {
    const float* nf    = (const float*)d_in[0];
    const int*   ei    = (const int*)d_in[1];
    const float* ne_w1 = (const float*)d_in[2];
    const float* ne_b1 = (const float*)d_in[3];
    const float* ne_w2 = (const float*)d_in[4];
    const float* ne_b2 = (const float*)d_in[5];
    const float* mw1   = (const float*)d_in[6];
    const float* mb1   = (const float*)d_in[7];
    const float* mw2   = (const float*)d_in[8];
    const float* mb2   = (const float*)d_in[9];
    const float* uw1   = (const float*)d_in[10];
    const float* ub1   = (const float*)d_in[11];
    const float* uw2   = (const float*)d_in[12];
    const float* ub2   = (const float*)d_in[13];
    const float* lng   = (const float*)d_in[14];
    const float* lnb   = (const float*)d_in[15];
    const float* rw1   = (const float*)d_in[16];
    const float* rb1   = (const float*)d_in[17];
    const float* rw2   = (const float*)d_in[18];
    const float* rb2   = (const float*)d_in[19];

    const int* e_src = ei;
    const int* e_dst = ei + NE;

    char* w = (char*)d_ws;
    size_t off = 0;
    auto alloc = [&](size_t bytes) -> void* {
        void* p = w + off;
        off = (off + bytes + 255) & ~(size_t)255;
        return p;
    };
    const size_t NF32 = (size_t)NN * HD * sizeof(float);
    const size_t NF16 = (size_t)NN * HD * sizeof(ushort_t);
    const size_t WM16 = (size_t)HD * HD * sizeof(ushort_t);

    float* x    = (float*)alloc(NF32);
    float* Qf   = (float*)alloc(NF32);
    float* gsum = (float*)alloc(HD * sizeof(float));
    float* degf = (float*)alloc(NN * sizeof(float));
    float* b2u1 = (float*)alloc(NL * HD * sizeof(float));

    ushort_t* nfT   = (ushort_t*)alloc(NF16);
    ushort_t* xb    = (ushort_t*)alloc(NF16);
    ushort_t* Pb    = (ushort_t*)alloc(NF16);
    ushort_t* Haggb = (ushort_t*)alloc(NF16);
    ushort_t* neT1  = (ushort_t*)alloc(WM16);
    ushort_t* neT2  = (ushort_t*)alloc(WM16);
    ushort_t* w1tT  = (ushort_t*)alloc(NL * WM16);
    ushort_t* w1bT  = (ushort_t*)alloc(NL * WM16);
    ushort_t* u1tT  = (ushort_t*)alloc(NL * WM16);
    ushort_t* u1bT  = (ushort_t*)alloc(NL * WM16);
    ushort_t* u2T   = (ushort_t*)alloc(NL * WM16);
    ushort_t* w2uT  = (ushort_t*)alloc(NL * WM16);
    ushort_t* w2rmb = (ushort_t*)alloc(NL * WM16);

    int* deg       = (int*)alloc(NN * sizeof(int));
    int* row_start = (int*)alloc((NN + 1) * sizeof(int));
    int* cursor    = (int*)alloc(NN * sizeof(int));
    int* srcs      = (int*)alloc(NE * sizeof(int));

    hipMemsetAsync(deg, 0, NN * sizeof(int), stream);

    // CSR build
    hist_deg<<<(NE + 255) / 256, 256, 0, stream>>>(e_dst, deg, NE);
    scan_csr<<<1, 1024, 0, stream>>>(deg, row_start, cursor, degf, gsum, NN);
    scatter_src<<<(NE + 255) / 256, 256, 0, stream>>>(e_src, e_dst, cursor, srcs, NE);

    // weight prep
    TArgs ta;
    ta.d[0] = { ne_w1, neT1, 2 };
    ta.d[1] = { ne_w2, neT2, 2 };
    for (int l = 0; l < NL; ++l) {
        const float* w1l = mw1 + (size_t)l * 2 * HD * HD;
        const float* u1l = uw1 + (size_t)l * 2 * HD * HD;
        ta.d[2 + l]  = { w1l,                       w1tT + (size_t)l * HD * HD, 2 };
        ta.d[5 + l]  = { w1l + (size_t)HD * HD,     w1bT + (size_t)l * HD * HD, 2 };
        ta.d[8 + l]  = { u1l,                       u1tT + (size_t)l * HD * HD, 2 };
        ta.d[11 + l] = { u1l + (size_t)HD * HD,     u1bT + (size_t)l * HD * HD, 1 };
        ta.d[14 + l] = { uw2 + (size_t)l * HD * HD, u2T + (size_t)l * HD * HD, 2 };
        ta.d[17 + l] = { mw2 + (size_t)l * HD * HD, w2rmb + (size_t)l * HD * HD, 0 };
    }
    conv_t<<<dim3(16, 20), 256, 0, stream>>>(ta);
    cast_nf_tiled<<<NN / 16, 256, 0, stream>>>(nf, nfT);
    bias_compose<<<NL, 256, 0, stream>>>(mb2, uw1, b2u1);
    gemm_w2u<<<dim3(4, 4, NL), 256, 0, stream>>>(u1bT, w2rmb, w2uT);

    // encoder + layer-0 P/Q
    enc_pq<<<NN / 16, 512, 0, stream>>>(nfT, neT1, neT2, ne_b1, ne_b2,
                                        w1tT, w1bT, mb1, x, xb, Pb, Qf, NN);

    for (int l = 0; l < NL; ++l) {
        edge_agg<<<NN / 8, 256, 0, stream>>>(Pb, Qf, row_start, srcs, Haggb);
        int nl = l + 1;
        const ushort_t* pw1t = (nl < NL) ? w1tT + (size_t)nl * HD * HD : nullptr;
        const ushort_t* pw1b = (nl < NL) ? w1bT + (size_t)nl * HD * HD : nullptr;
        const float*    pqb1 = (nl < NL) ? mb1 + (size_t)nl * HD : nullptr;
        float* gs = (l == NL - 1) ? gsum : nullptr;
        upd_ln<<<NN / 16, 512, 0, stream>>>(
            xb, Haggb, u1tT + (size_t)l * HD * HD, w2uT + (size_t)l * HD * HD,
            u2T + (size_t)l * HD * HD, degf,
            ub1 + (size_t)l * HD, b2u1 + (size_t)l * HD, ub2 + (size_t)l * HD,
            lng + (size_t)l * HD, lnb + (size_t)l * HD,
            pw1t, pw1b, pqb1, gs, x, xb, Pb, Qf, NN);
    }

    // readout
    readout_mlp<<<1, 256, 0, stream>>>(gsum, rw1, rb1, rw2, rb2, (float*)d_out, 1.0f / NN);
}

// Round 16
// 273.599 us; speedup vs baseline: 1.1476x; 1.0371x over previous
//
#include <hip/hip_runtime.h>

#define NN 10000
#define NE 320000
#define HD 256
#define NL 3

typedef unsigned short ushort_t;
typedef __attribute__((ext_vector_type(8))) short bf16x8;
typedef __attribute__((ext_vector_type(4))) float f32x4;

#define MFMA __builtin_amdgcn_mfma_f32_16x16x32_bf16

#define WAITV(N) asm volatile("s_waitcnt vmcnt(" #N ")" ::: "memory")
#define SCHEDPIN() __builtin_amdgcn_sched_barrier(0)
#define LGKMBAR() do { asm volatile("s_waitcnt lgkmcnt(0)" ::: "memory"); \
                       __builtin_amdgcn_s_barrier(); __builtin_amdgcn_sched_barrier(0); } while (0)

__device__ __forceinline__ unsigned short f2bf(float x) {
    unsigned u = __float_as_uint(x);
    unsigned rounding = 0x7FFFu + ((u >> 16) & 1u);
    return (unsigned short)((u + rounding) >> 16);
}
__device__ __forceinline__ float bf2f(unsigned short u) {
    return __uint_as_float(((unsigned)u) << 16);
}
__device__ __forceinline__ int sw2(int col) { return (col & 3) ^ ((col >> 2) & 3); }
__device__ __forceinline__ void dma16(const void* g, void* l) {
    __builtin_amdgcn_global_load_lds(
        (const __attribute__((address_space(1))) unsigned int*)g,
        (__attribute__((address_space(3))) unsigned int*)l, 16, 0, 0);
}

// ---------------- CSR scan (single block; order-dependent) ----------------

__global__ __launch_bounds__(1024) void scan_csr(const int* __restrict__ deg,
                                                 int* __restrict__ row_start,
                                                 int* __restrict__ cursor,
                                                 float* __restrict__ degf,
                                                 float* __restrict__ gsum, int n) {
    __shared__ int wsum[16];
    __shared__ int carry_s;
    int tid = threadIdx.x, lane = tid & 63, wid = tid >> 6;
    if (tid < HD) gsum[tid] = 0.f;
    if (tid == 0) carry_s = 0;
    __syncthreads();
    for (int base = 0; base < n; base += 1024) {
        int i = base + tid;
        int v = (i < n) ? deg[i] : 0;
        int s = v;
        #pragma unroll
        for (int off = 1; off < 64; off <<= 1) {
            int t = __shfl_up(s, off);
            if (lane >= off) s += t;
        }
        if (lane == 63) wsum[wid] = s;
        __syncthreads();
        if (wid == 0 && lane < 16) {
            int ws = wsum[lane];
            #pragma unroll
            for (int off = 1; off < 16; off <<= 1) {
                int t = __shfl_up(ws, off);
                if (lane >= off) ws += t;
            }
            wsum[lane] = ws;
        }
        __syncthreads();
        int carry = carry_s;
        int wpre = (wid > 0) ? wsum[wid - 1] : 0;
        int incl = carry + wpre + s;
        int excl = incl - v;
        if (i < n) { row_start[i] = excl; cursor[i] = excl; degf[i] = (float)v; }
        __syncthreads();
        if (tid == 1023) carry_s = incl;
        __syncthreads();
    }
    if (tid == 0) row_start[n] = carry_s;
}

// ---------------- prep1: hist_deg || conv_t || cast_nf || bias_compose ----------------
// mode 0: straight cast; mode 1: transpose row-major; mode 2: transpose + K-sliced tile

struct TDesc { const float* src; ushort_t* dst; int mode; };
struct TArgs { TDesc d[20]; };

#define HIST_BLKS 1250
#define CONV_BLKS 320
#define CAST_BLKS 625

__global__ __launch_bounds__(256) void prep1(
    const int* __restrict__ edst, int* __restrict__ deg,
    TArgs args,
    const float* __restrict__ nf, ushort_t* __restrict__ nfT,
    const float* __restrict__ mb2, const float* __restrict__ uw1,
    float* __restrict__ b2u1)
{
    __shared__ ushort_t tile[64][65];
    int b = blockIdx.x;
    int tid = threadIdx.x;

    if (b < HIST_BLKS) {                       // ---- hist_deg ----
        int e = b * 256 + tid;
        if (e < NE) atomicAdd(&deg[edst[e]], 1);
        return;
    }
    b -= HIST_BLKS;
    if (b < CONV_BLKS) {                       // ---- conv_t ----
        const float* src = args.d[b >> 4].src;
        ushort_t* dst = args.d[b >> 4].dst;
        int mode = args.d[b >> 4].mode;
        int t = b & 15;
        int r0 = (t >> 2) * 64, c0 = (t & 3) * 64;
        int rr = tid >> 4, cc4 = (tid & 15) * 4;
        if (mode == 0) {
            #pragma unroll
            for (int i = 0; i < 4; ++i) {
                int r = r0 + rr + i * 16;
                float4 v = *(const float4*)(src + (size_t)r * HD + c0 + cc4);
                ushort4 o = { f2bf(v.x), f2bf(v.y), f2bf(v.z), f2bf(v.w) };
                *(ushort4*)(dst + (size_t)r * HD + c0 + cc4) = o;
            }
            return;
        }
        #pragma unroll
        for (int i = 0; i < 4; ++i) {
            int r = rr + i * 16;
            float4 v = *(const float4*)(src + (size_t)(r0 + r) * HD + c0 + cc4);
            tile[cc4 + 0][r] = f2bf(v.x);
            tile[cc4 + 1][r] = f2bf(v.y);
            tile[cc4 + 2][r] = f2bf(v.z);
            tile[cc4 + 3][r] = f2bf(v.w);
        }
        __syncthreads();
        #pragma unroll
        for (int i = 0; i < 4; ++i) {
            int c = rr + i * 16;
            ushort4 o = { tile[c][cc4], tile[c][cc4 + 1], tile[c][cc4 + 2], tile[c][cc4 + 3] };
            if (mode == 1) {
                *(ushort4*)(dst + (size_t)(c0 + c) * HD + r0 + cc4) = o;
            } else {
                int col = c0 + c;
                int k = r0 + cc4;
                int s = k >> 5, qv = (k >> 3) & 3;
                int slot = qv ^ sw2(col);
                *(ushort4*)(dst + (size_t)s * 8192 + col * 32 + slot * 8 + (k & 7)) = o;
            }
        }
        return;
    }
    b -= CONV_BLKS;
    if (b < CAST_BLKS) {                       // ---- cast_nf_tiled ----
        int row = tid >> 4, gg = tid & 15;
        const float* sp = nf + ((size_t)b * 16 + row) * HD + gg * 16;
        ushort_t* dp = nfT + (size_t)b * 4096 + (gg >> 1) * 512 + row * 32 + (gg & 1) * 16;
        #pragma unroll
        for (int j = 0; j < 4; ++j) {
            float4 v = *(const float4*)(sp + j * 4);
            ushort4 o = { f2bf(v.x), f2bf(v.y), f2bf(v.z), f2bf(v.w) };
            *(ushort4*)(dp + j * 4) = o;
        }
        return;
    }
    b -= CAST_BLKS;
    {                                          // ---- bias_compose (NL blocks) ----
        int l = b, c = tid;
        const float* b2l = mb2 + (size_t)l * HD;
        const float* u1b = uw1 + (size_t)l * 2 * HD * HD + (size_t)HD * HD;
        float s = 0.f;
        for (int k = 0; k < HD; ++k) s += b2l[k] * u1b[(size_t)k * HD + c];
        b2u1[(size_t)l * HD + c] = s;
    }
}

// ---------------- prep2: scatter_src || gemm_w2u ----------------

__global__ __launch_bounds__(256) void prep2(
    const int* __restrict__ esrc, const int* __restrict__ edst,
    int* __restrict__ cursor, int* __restrict__ src_sorted,
    const ushort_t* __restrict__ Abase, const ushort_t* __restrict__ Btbase,
    ushort_t* __restrict__ outBase)
{
    int b = blockIdx.x;
    int tid = threadIdx.x;
    if (b < HIST_BLKS) {                       // ---- scatter_src ----
        int e = b * 256 + tid;
        if (e < NE) {
            int pos = atomicAdd(&cursor[edst[e]], 1);
            src_sorted[pos] = esrc[e];
        }
        return;
    }
    int i = b - HIST_BLKS;                     // ---- gemm_w2u (48 blocks) ----
    int bx = i & 3, by = (i >> 2) & 3, bz = i >> 4;
    const ushort_t* A  = Abase  + (size_t)bz * HD * HD;
    const ushort_t* Bt = Btbase + (size_t)bz * HD * HD;
    ushort_t* outB     = outBase + (size_t)bz * HD * HD;
    int wid = tid >> 6, lane = tid & 63;
    int wm = wid >> 1, wn = wid & 1;
    int row0 = bx * 64 + wm * 32;
    int col0 = by * 64 + wn * 32;
    int lm = lane & 15, lk = (lane >> 4) * 8;
    f32x4 acc[2][2] = {};
    const ushort_t* a0p = A + (size_t)(row0 + lm) * HD + lk;
    const ushort_t* a1p = A + (size_t)(row0 + 16 + lm) * HD + lk;
    const ushort_t* b0p = Bt + (size_t)(col0 + lm) * HD + lk;
    const ushort_t* b1p = Bt + (size_t)(col0 + 16 + lm) * HD + lk;
    #pragma unroll
    for (int k0 = 0; k0 < HD; k0 += 32) {
        bf16x8 a0 = *(const bf16x8*)(a0p + k0);
        bf16x8 a1 = *(const bf16x8*)(a1p + k0);
        bf16x8 b0 = *(const bf16x8*)(b0p + k0);
        bf16x8 b1 = *(const bf16x8*)(b1p + k0);
        acc[0][0] = MFMA(a0, b0, acc[0][0], 0, 0, 0);
        acc[0][1] = MFMA(a0, b1, acc[0][1], 0, 0, 0);
        acc[1][0] = MFMA(a1, b0, acc[1][0], 0, 0, 0);
        acc[1][1] = MFMA(a1, b1, acc[1][1], 0, 0, 0);
    }
    int orow = (lane >> 4) * 4;
    #pragma unroll
    for (int mi = 0; mi < 2; ++mi)
        #pragma unroll
        for (int r = 0; r < 4; ++r) {
            int row = row0 + mi * 16 + orow + r;        // n
            #pragma unroll
            for (int ni = 0; ni < 2; ++ni) {
                int col = col0 + ni * 16 + lm;          // k
                int s = col >> 5, qv = (col >> 3) & 3;
                int slot = qv ^ sw2(row);
                outB[(size_t)s * 8192 + row * 32 + slot * 8 + (col & 7)] = f2bf(acc[mi][ni][r]);
            }
        }
}

// ---------------- LDS swizzle for hid [16 rows][512B] ----------------
__device__ __forceinline__ int swz(int row, int byte_in_row) {
    return row * 512 + (byte_in_row ^ ((row & 7) << 4));
}

// ---------------- fused encoder + layer-0 P/Q (tiled operands, contiguous DMA) ----------------

__global__ __launch_bounds__(512, 4) void enc_pq(
    const ushort_t* __restrict__ Anf, const ushort_t* __restrict__ B1t,
    const ushort_t* __restrict__ B2t,
    const float* __restrict__ b1, const float* __restrict__ b2,
    const ushort_t* __restrict__ Pw1t, const ushort_t* __restrict__ Pw1b,
    const float* __restrict__ pqb1,
    float* __restrict__ xF, ushort_t* __restrict__ xB,
    ushort_t* __restrict__ P, float* __restrict__ Q, int M)
{
    __shared__ char wlds[8][2][2][2048];
    __shared__ char hid[16 * 512];
    int tid = threadIdx.x;
    int w = tid >> 6, lane = tid & 63;
    int lm = lane & 15, q = lane >> 4;
    int row0 = blockIdx.x * 16;
    int col0 = w * 32;
    int cA = col0 + lm, cB = col0 + 16 + lm;

    auto stageW = [&](const ushort_t* Wt, int s, int p, int m) {
        #pragma unroll
        for (int i = 0; i < 2; ++i)
            dma16((const char*)Wt + (size_t)s * 16384 + (col0 + 16 * i) * 64 + lane * 16,
                  wlds[w][p][m] + i * 1024);
    };
    auto readB = [&](int p, int m, int ni) -> bf16x8 {
        int col = col0 + 16 * ni + lm;
        int q2 = q ^ sw2(col);
        return *(const bf16x8*)(wlds[w][p][m] + ni * 1024 + lm * 64 + q2 * 16);
    };

    float b1v[2] = { b1[cA], b1[cB] };
    float b2v[2] = { b2[cA], b2[cB] };
    float pqv[2] = { pqb1[cA], pqb1[cB] };

    const ushort_t* ap = Anf + (size_t)blockIdx.x * 4096 + lm * 32 + q * 8;
    bf16x8 ax[2];
    #pragma unroll
    for (int s = 0; s < 2; ++s) {
        stageW(B1t, s, s, 0);
        ax[s] = *(const bf16x8*)(ap + s * 512);
        SCHEDPIN();
    }

    // ---- pass 1: acc = nf @ W1 ----
    f32x4 acc[2] = {};
    #pragma unroll
    for (int j = 0; j < 8; ++j) {
        int p = j & 1;
        if (j < 7) { WAITV(3); } else { WAITV(0); }
        acc[0] = MFMA(ax[p], readB(p, 0, 0), acc[0], 0, 0, 0);
        acc[1] = MFMA(ax[p], readB(p, 0, 1), acc[1], 0, 0, 0);
        SCHEDPIN();
        if (j < 6) {
            stageW(B1t, j + 2, p, 0);
            ax[p] = *(const bf16x8*)(ap + (j + 2) * 512);
            SCHEDPIN();
        }
    }

    #pragma unroll
    for (int s = 0; s < 2; ++s) { stageW(B2t, s, s, 0); SCHEDPIN(); }
    #pragma unroll
    for (int ni = 0; ni < 2; ++ni) {
        int col = col0 + 16 * ni + lm;
        #pragma unroll
        for (int r = 0; r < 4; ++r) {
            int row = 4 * q + r;
            float v = fmaxf(acc[ni][r] + b1v[ni], 0.f);
            *(ushort_t*)(hid + swz(row, col * 2)) = f2bf(v);
        }
    }
    LGKMBAR();

    // ---- pass 2: acc2 = hid @ W2 ----
    f32x4 acc2[2] = {};
    #pragma unroll
    for (int j = 0; j < 8; ++j) {
        int p = j & 1;
        if (j < 7) { WAITV(2); } else { WAITV(0); }
        int bk = (j * 32 + q * 8) * 2;
        bf16x8 a = *(const bf16x8*)(hid + swz(lm, bk));
        acc2[0] = MFMA(a, readB(p, 0, 0), acc2[0], 0, 0, 0);
        acc2[1] = MFMA(a, readB(p, 0, 1), acc2[1], 0, 0, 0);
        SCHEDPIN();
        if (j < 6) { stageW(B2t, j + 2, p, 0); SCHEDPIN(); }
    }

    // PQ prologue; xstage after all pass-2 hid reads
    #pragma unroll
    for (int s = 0; s < 2; ++s) {
        stageW(Pw1t, s, s, 0);
        stageW(Pw1b, s, s, 1);
        SCHEDPIN();
    }
    LGKMBAR();
    int tbase = blockIdx.x * 4096 + w * 512;
    #pragma unroll
    for (int ni = 0; ni < 2; ++ni) {
        int col = col0 + 16 * ni + lm;
        #pragma unroll
        for (int r = 0; r < 4; ++r) {
            int row = 4 * q + r;
            int grow = row0 + row;
            float v = acc2[ni][r] + b2v[ni];
            *(ushort_t*)(hid + swz(row, col * 2)) = f2bf(v);
            xF[(size_t)grow * HD + col] = v;
            xB[tbase + row * 32 + 16 * ni + lm] = f2bf(v);
        }
    }
    LGKMBAR();

    // ---- PQ pass ----
    f32x4 aP[2] = {}, aQ[2] = {};
    #pragma unroll
    for (int j = 0; j < 8; ++j) {
        int p = j & 1;
        if (j < 7) { WAITV(4); } else { WAITV(0); }
        int bk = (j * 32 + q * 8) * 2;
        bf16x8 a = *(const bf16x8*)(hid + swz(lm, bk));
        #pragma unroll
        for (int ni = 0; ni < 2; ++ni) {
            aP[ni] = MFMA(a, readB(p, 0, ni), aP[ni], 0, 0, 0);
            aQ[ni] = MFMA(a, readB(p, 1, ni), aQ[ni], 0, 0, 0);
        }
        SCHEDPIN();
        if (j < 6) {
            stageW(Pw1t, j + 2, p, 0);
            stageW(Pw1b, j + 2, p, 1);
            SCHEDPIN();
        }
    }
    #pragma unroll
    for (int r = 0; r < 4; ++r) {
        int grow = row0 + 4 * q + r;
        #pragma unroll
        for (int ni = 0; ni < 2; ++ni) {
            int col = col0 + 16 * ni + lm;
            P[(size_t)grow * HD + col] = f2bf(aP[ni][r]);
            Q[(size_t)grow * HD + col] = aQ[ni][r] + pqv[ni];
        }
    }
}

// ---------------- edge aggregation (2 nodes/wave, interleaved streams) ----------------

__global__ __launch_bounds__(256) void edge_agg(
    const ushort_t* __restrict__ Pb, const float* __restrict__ Qf,
    const int* __restrict__ row_start, const int* __restrict__ srcs,
    ushort_t* __restrict__ HaggT)
{
    int wv = blockIdx.x * 4 + (threadIdx.x >> 6);
    int lane = threadIdx.x & 63;
    int c4 = lane * 4;
    int n0 = wv * 2, n1 = n0 + 1;
    float4 qb0 = *(const float4*)(Qf + (size_t)n0 * HD + c4);
    float4 qb1 = *(const float4*)(Qf + (size_t)n1 * HD + c4);
    float4 A0 = {0.f, 0.f, 0.f, 0.f}, A1 = {0.f, 0.f, 0.f, 0.f};
    int j0 = row_start[n0], e0 = row_start[n0 + 1];
    int j1 = row_start[n1], e1 = row_start[n1 + 1];
    while (j0 + 4 <= e0 && j1 + 4 <= e1) {
        ushort4 p[8];
        #pragma unroll
        for (int u = 0; u < 4; ++u)
            p[u] = *(const ushort4*)(Pb + (size_t)srcs[j0 + u] * HD + c4);
        #pragma unroll
        for (int u = 0; u < 4; ++u)
            p[4 + u] = *(const ushort4*)(Pb + (size_t)srcs[j1 + u] * HD + c4);
        #pragma unroll
        for (int u = 0; u < 4; ++u) {
            A0.x += fmaxf(bf2f(p[u].x) + qb0.x, 0.f);
            A0.y += fmaxf(bf2f(p[u].y) + qb0.y, 0.f);
            A0.z += fmaxf(bf2f(p[u].z) + qb0.z, 0.f);
            A0.w += fmaxf(bf2f(p[u].w) + qb0.w, 0.f);
            A1.x += fmaxf(bf2f(p[4 + u].x) + qb1.x, 0.f);
            A1.y += fmaxf(bf2f(p[4 + u].y) + qb1.y, 0.f);
            A1.z += fmaxf(bf2f(p[4 + u].z) + qb1.z, 0.f);
            A1.w += fmaxf(bf2f(p[4 + u].w) + qb1.w, 0.f);
        }
        j0 += 4; j1 += 4;
    }
    for (; j0 + 4 <= e0; j0 += 4) {
        ushort4 p[4];
        #pragma unroll
        for (int u = 0; u < 4; ++u)
            p[u] = *(const ushort4*)(Pb + (size_t)srcs[j0 + u] * HD + c4);
        #pragma unroll
        for (int u = 0; u < 4; ++u) {
            A0.x += fmaxf(bf2f(p[u].x) + qb0.x, 0.f);
            A0.y += fmaxf(bf2f(p[u].y) + qb0.y, 0.f);
            A0.z += fmaxf(bf2f(p[u].z) + qb0.z, 0.f);
            A0.w += fmaxf(bf2f(p[u].w) + qb0.w, 0.f);
        }
    }
    for (; j0 < e0; ++j0) {
        ushort4 p0 = *(const ushort4*)(Pb + (size_t)srcs[j0] * HD + c4);
        A0.x += fmaxf(bf2f(p0.x) + qb0.x, 0.f);
        A0.y += fmaxf(bf2f(p0.y) + qb0.y, 0.f);
        A0.z += fmaxf(bf2f(p0.z) + qb0.z, 0.f);
        A0.w += fmaxf(bf2f(p0.w) + qb0.w, 0.f);
    }
    for (; j1 + 4 <= e1; j1 += 4) {
        ushort4 p[4];
        #pragma unroll
        for (int u = 0; u < 4; ++u)
            p[u] = *(const ushort4*)(Pb + (size_t)srcs[j1 + u] * HD + c4);
        #pragma unroll
        for (int u = 0; u < 4; ++u) {
            A1.x += fmaxf(bf2f(p[u].x) + qb1.x, 0.f);
            A1.y += fmaxf(bf2f(p[u].y) + qb1.y, 0.f);
            A1.z += fmaxf(bf2f(p[u].z) + qb1.z, 0.f);
            A1.w += fmaxf(bf2f(p[u].w) + qb1.w, 0.f);
        }
    }
    for (; j1 < e1; ++j1) {
        ushort4 p0 = *(const ushort4*)(Pb + (size_t)srcs[j1] * HD + c4);
        A1.x += fmaxf(bf2f(p0.x) + qb1.x, 0.f);
        A1.y += fmaxf(bf2f(p0.y) + qb1.y, 0.f);
        A1.z += fmaxf(bf2f(p0.z) + qb1.z, 0.f);
        A1.w += fmaxf(bf2f(p0.w) + qb1.w, 0.f);
    }
    ushort4 o0 = { f2bf(A0.x), f2bf(A0.y), f2bf(A0.z), f2bf(A0.w) };
    ushort4 o1 = { f2bf(A1.x), f2bf(A1.y), f2bf(A1.z), f2bf(A1.w) };
    int t0 = (n0 >> 4) * 4096 + (c4 >> 5) * 512 + (n0 & 15) * 32 + (c4 & 31);
    int t1 = (n1 >> 4) * 4096 + (c4 >> 5) * 512 + (n1 & 15) * 32 + (c4 & 31);
    *(ushort4*)(HaggT + t0) = o0;
    *(ushort4*)(HaggT + t1) = o1;
}

// ---------------- fused update + LN + next P/Q (tiled operands, contiguous DMA) ----------------

__global__ __launch_bounds__(512, 4) void upd_ln(
    const ushort_t* __restrict__ xb, const ushort_t* __restrict__ Hb,
    const ushort_t* __restrict__ B1t, const ushort_t* __restrict__ B2t,
    const ushort_t* __restrict__ B3t,
    const float* __restrict__ degf,
    const float* __restrict__ b1, const float* __restrict__ bias2,
    const float* __restrict__ b3,
    const float* __restrict__ g, const float* __restrict__ bb,
    const ushort_t* __restrict__ Pw1t, const ushort_t* __restrict__ Pw1b,
    const float* __restrict__ pqb1,
    float* __restrict__ gsum,
    float* __restrict__ xF, ushort_t* __restrict__ xB,
    ushort_t* __restrict__ P, float* __restrict__ Q, int M)
{
    __shared__ char wlds[8][2][2][2048];
    __shared__ char hid[16 * 512];
    __shared__ float sS[8][16], sQ[8][16], muv[16], ivv[16];

    int tid = threadIdx.x;
    int w = tid >> 6, lane = tid & 63;
    int lm = lane & 15, q = lane >> 4;
    int row0 = blockIdx.x * 16;
    int col0 = w * 32;
    int cA = col0 + lm, cB = col0 + 16 + lm;

    auto stageW = [&](const ushort_t* Wt, int s, int p, int m) {
        #pragma unroll
        for (int i = 0; i < 2; ++i)
            dma16((const char*)Wt + (size_t)s * 16384 + (col0 + 16 * i) * 64 + lane * 16,
                  wlds[w][p][m] + i * 1024);
    };
    auto readB = [&](int p, int m, int ni) -> bf16x8 {
        int col = col0 + 16 * ni + lm;
        int q2 = q ^ sw2(col);
        return *(const bf16x8*)(wlds[w][p][m] + ni * 1024 + lm * 64 + q2 * 16);
    };

    const ushort_t* xp = xb + (size_t)blockIdx.x * 4096 + lm * 32 + q * 8;
    const ushort_t* hp = Hb + (size_t)blockIdx.x * 4096 + lm * 32 + q * 8;
    bf16x8 ax[2], ah[2];
    #pragma unroll
    for (int s = 0; s < 2; ++s) {
        stageW(B1t, s, s, 0);
        stageW(B2t, s, s, 1);
        ax[s] = *(const bf16x8*)(xp + s * 512);
        ah[s] = *(const bf16x8*)(hp + s * 512);
        SCHEDPIN();
    }

    float b1v[2] = { b1[cA], b1[cB] };
    float bzv[2] = { bias2[cA], bias2[cB] };
    float b3v[2] = { b3[cA], b3[cB] };
    float gv[2]  = { g[cA],  g[cB]  };
    float bbv[2] = { bb[cA], bb[cB] };
    float pqv[2] = { Pw1t ? pqb1[cA] : 0.f, Pw1t ? pqb1[cB] : 0.f };
    float dgv[4], res[2][4];
    #pragma unroll
    for (int r = 0; r < 4; ++r) {
        int row = 4 * q + r;
        dgv[r] = degf[row0 + row];
        res[0][r] = xF[(size_t)(row0 + row) * HD + cA];
        res[1][r] = xF[(size_t)(row0 + row) * HD + cB];
    }

    // ---- pass 1+2: acc = x@u1t + Hagg@w2u ----
    f32x4 acc[2] = {};
    #pragma unroll
    for (int j = 0; j < 8; ++j) {
        int p = j & 1;
        if (j < 7) { WAITV(6); } else { WAITV(0); }
        #pragma unroll
        for (int ni = 0; ni < 2; ++ni) {
            acc[ni] = MFMA(ax[p], readB(p, 0, ni), acc[ni], 0, 0, 0);
            acc[ni] = MFMA(ah[p], readB(p, 1, ni), acc[ni], 0, 0, 0);
        }
        SCHEDPIN();
        if (j < 6) {
            stageW(B1t, j + 2, p, 0);
            stageW(B2t, j + 2, p, 1);
            ax[p] = *(const bf16x8*)(xp + (j + 2) * 512);
            ah[p] = *(const bf16x8*)(hp + (j + 2) * 512);
            SCHEDPIN();
        }
    }

    // transition: u2 prologue over hid build
    #pragma unroll
    for (int s = 0; s < 2; ++s) { stageW(B3t, s, s, 0); SCHEDPIN(); }
    #pragma unroll
    for (int r = 0; r < 4; ++r) {
        int row = 4 * q + r;
        #pragma unroll
        for (int ni = 0; ni < 2; ++ni) {
            int col = col0 + 16 * ni + lm;
            float v = fmaxf(acc[ni][r] + b1v[ni] + dgv[r] * bzv[ni], 0.f);
            *(ushort_t*)(hid + swz(row, col * 2)) = f2bf(v);
        }
    }
    LGKMBAR();

    // ---- pass 3: upd = hid @ u2 ----
    f32x4 acc2[2] = {};
    #pragma unroll
    for (int j = 0; j < 8; ++j) {
        int p = j & 1;
        if (j < 7) { WAITV(2); } else { WAITV(0); }
        int bk = (j * 32 + q * 8) * 2;
        bf16x8 a = *(const bf16x8*)(hid + swz(lm, bk));
        acc2[0] = MFMA(a, readB(p, 0, 0), acc2[0], 0, 0, 0);
        acc2[1] = MFMA(a, readB(p, 0, 1), acc2[1], 0, 0, 0);
        SCHEDPIN();
        if (j < 6) { stageW(B3t, j + 2, p, 0); SCHEDPIN(); }
    }

    // PQ prologue over LN
    if (Pw1t) {
        #pragma unroll
        for (int s = 0; s < 2; ++s) {
            stageW(Pw1t, s, s, 0);
            stageW(Pw1b, s, s, 1);
            SCHEDPIN();
        }
    }
    // v = x + upd + ub2; LN partials
    #pragma unroll
    for (int r = 0; r < 4; ++r) {
        float s = 0.f, qq = 0.f;
        #pragma unroll
        for (int ni = 0; ni < 2; ++ni) {
            float v = acc2[ni][r] + b3v[ni] + res[ni][r];
            acc2[ni][r] = v;
            s += v; qq += v * v;
        }
        #pragma unroll
        for (int off = 1; off < 16; off <<= 1) {
            s += __shfl_xor(s, off);
            qq += __shfl_xor(qq, off);
        }
        if (lm == 0) {
            int row = 4 * q + r;
            sS[w][row] = s; sQ[w][row] = qq;
        }
    }
    LGKMBAR();
    if (tid < 16) {
        float s = 0.f, qq = 0.f;
        #pragma unroll
        for (int i = 0; i < 8; ++i) { s += sS[i][tid]; qq += sQ[i][tid]; }
        float mu = s * (1.0f / HD);
        float var = qq * (1.0f / HD) - mu * mu;
        muv[tid] = mu;
        ivv[tid] = rsqrtf(var + 1e-5f);
    }
    LGKMBAR();
    // LN final + stores + xstage + colsum partials
    float csum[2] = {0.f, 0.f};
    int tbase = blockIdx.x * 4096 + w * 512;
    #pragma unroll
    for (int r = 0; r < 4; ++r) {
        int row = 4 * q + r;
        int grow = row0 + row;
        float mu = muv[row], iv = ivv[row];
        #pragma unroll
        for (int ni = 0; ni < 2; ++ni) {
            int col = col0 + 16 * ni + lm;
            float o = (acc2[ni][r] - mu) * iv * gv[ni] + bbv[ni];
            *(ushort_t*)(hid + swz(row, col * 2)) = f2bf(o);
            xF[(size_t)grow * HD + col] = o;
            xB[tbase + row * 32 + 16 * ni + lm] = f2bf(o);
            csum[ni] += o;
        }
    }
    if (gsum) {
        #pragma unroll
        for (int ni = 0; ni < 2; ++ni) {
            float s = csum[ni];
            s += __shfl_xor(s, 16);
            s += __shfl_xor(s, 32);
            if (q == 0) atomicAdd(&gsum[col0 + 16 * ni + lm], s);
        }
    }

    // ---- PQ pass ----
    if (Pw1t) {
        LGKMBAR();
        f32x4 aP[2] = {}, aQ[2] = {};
        #pragma unroll
        for (int j = 0; j < 8; ++j) {
            int p = j & 1;
            if (j < 7) { WAITV(4); } else { WAITV(0); }
            int bk = (j * 32 + q * 8) * 2;
            bf16x8 a = *(const bf16x8*)(hid + swz(lm, bk));
            #pragma unroll
            for (int ni = 0; ni < 2; ++ni) {
                aP[ni] = MFMA(a, readB(p, 0, ni), aP[ni], 0, 0, 0);
                aQ[ni] = MFMA(a, readB(p, 1, ni), aQ[ni], 0, 0, 0);
            }
            SCHEDPIN();
            if (j < 6) {
                stageW(Pw1t, j + 2, p, 0);
                stageW(Pw1b, j + 2, p, 1);
                SCHEDPIN();
            }
        }
        #pragma unroll
        for (int r = 0; r < 4; ++r) {
            int grow = row0 + 4 * q + r;
            #pragma unroll
            for (int ni = 0; ni < 2; ++ni) {
                int col = col0 + 16 * ni + lm;
                P[(size_t)grow * HD + col] = f2bf(aP[ni][r]);
                Q[(size_t)grow * HD + col] = aQ[ni][r] + pqv[ni];
            }
        }
    }
}

// ---------------- readout ----------------

__global__ __launch_bounds__(256) void readout_mlp(
    const float* __restrict__ gsum,
    const float* __restrict__ w1, const float* __restrict__ b1,
    const float* __restrict__ w2, const float* __restrict__ b2,
    float* __restrict__ out, float invn)
{
    __shared__ float gl[HD], h1[HD];
    int c = threadIdx.x;
    gl[c] = gsum[c] * invn;
    __syncthreads();
    float a = b1[c];
    for (int k = 0; k < HD; ++k) a += gl[k] * w1[k * HD + c];
    h1[c] = fmaxf(a, 0.f);
    __syncthreads();
    float o = b2[c];
    for (int k = 0; k < HD; ++k) o += h1[k] * w2[k * HD + c];
    out[c] = o;
}

// ---------------- orchestration ----------------

extern "C" void kernel_launch(void* const* d_in, const int* in_sizes, int n_in,
                              void* d_out, int out_size, void* d_ws, size_t ws_size,
                              hipStream_t stream) {
    const float* nf    = (const float*)d_in[0];
    const int*   ei    = (const int*)d_in[1];
    const float* ne_w1 = (const float*)d_in[2];
    const float* ne_b1 = (const float*)d_in[3];
    const float* ne_w2 = (const float*)d_in[4];
    const float* ne_b2 = (const float*)d_in[5];
    const float* mw1   = (const float*)d_in[6];
    const float* mb1   = (const float*)d_in[7];
    const float* mw2   = (const float*)d_in[8];
    const float* mb2   = (const float*)d_in[9];
    const float* uw1   = (const float*)d_in[10];
    const float* ub1   = (const float*)d_in[11];
    const float* uw2   = (const float*)d_in[12];
    const float* ub2   = (const float*)d_in[13];
    const float* lng   = (const float*)d_in[14];
    const float* lnb   = (const float*)d_in[15];
    const float* rw1   = (const float*)d_in[16];
    const float* rb1   = (const float*)d_in[17];
    const float* rw2   = (const float*)d_in[18];
    const float* rb2   = (const float*)d_in[19];

    const int* e_src = ei;
    const int* e_dst = ei + NE;

    char* w = (char*)d_ws;
    size_t off = 0;
    auto alloc = [&](size_t bytes) -> void* {
        void* p = w + off;
        off = (off + bytes + 255) & ~(size_t)255;
        return p;
    };
    const size_t NF32 = (size_t)NN * HD * sizeof(float);
    const size_t NF16 = (size_t)NN * HD * sizeof(ushort_t);
    const size_t WM16 = (size_t)HD * HD * sizeof(ushort_t);

    float* x    = (float*)alloc(NF32);
    float* Qf   = (float*)alloc(NF32);
    float* gsum = (float*)alloc(HD * sizeof(float));
    float* degf = (float*)alloc(NN * sizeof(float));
    float* b2u1 = (float*)alloc(NL * HD * sizeof(float));

    ushort_t* nfT   = (ushort_t*)alloc(NF16);
    ushort_t* xb    = (ushort_t*)alloc(NF16);
    ushort_t* Pb    = (ushort_t*)alloc(NF16);
    ushort_t* Haggb = (ushort_t*)alloc(NF16);
    ushort_t* neT1  = (ushort_t*)alloc(WM16);
    ushort_t* neT2  = (ushort_t*)alloc(WM16);
    ushort_t* w1tT  = (ushort_t*)alloc(NL * WM16);
    ushort_t* w1bT  = (ushort_t*)alloc(NL * WM16);
    ushort_t* u1tT  = (ushort_t*)alloc(NL * WM16);
    ushort_t* u1bT  = (ushort_t*)alloc(NL * WM16);
    ushort_t* u2T   = (ushort_t*)alloc(NL * WM16);
    ushort_t* w2uT  = (ushort_t*)alloc(NL * WM16);
    ushort_t* w2rmb = (ushort_t*)alloc(NL * WM16);

    int* deg       = (int*)alloc(NN * sizeof(int));
    int* row_start = (int*)alloc((NN + 1) * sizeof(int));
    int* cursor    = (int*)alloc(NN * sizeof(int));
    int* srcs      = (int*)alloc(NE * sizeof(int));

    hipMemsetAsync(deg, 0, NN * sizeof(int), stream);

    // prep1: hist_deg || conv_t (20 mats) || cast_nf || bias_compose
    TArgs ta;
    ta.d[0] = { ne_w1, neT1, 2 };
    ta.d[1] = { ne_w2, neT2, 2 };
    for (int l = 0; l < NL; ++l) {
        const float* w1l = mw1 + (size_t)l * 2 * HD * HD;
        const float* u1l = uw1 + (size_t)l * 2 * HD * HD;
        ta.d[2 + l]  = { w1l,                       w1tT + (size_t)l * HD * HD, 2 };
        ta.d[5 + l]  = { w1l + (size_t)HD * HD,     w1bT + (size_t)l * HD * HD, 2 };
        ta.d[8 + l]  = { u1l,                       u1tT + (size_t)l * HD * HD, 2 };
        ta.d[11 + l] = { u1l + (size_t)HD * HD,     u1bT + (size_t)l * HD * HD, 1 };
        ta.d[14 + l] = { uw2 + (size_t)l * HD * HD, u2T + (size_t)l * HD * HD, 2 };
        ta.d[17 + l] = { mw2 + (size_t)l * HD * HD, w2rmb + (size_t)l * HD * HD, 0 };
    }
    prep1<<<HIST_BLKS + CONV_BLKS + CAST_BLKS + NL, 256, 0, stream>>>(
        e_dst, deg, ta, nf, nfT, mb2, uw1, b2u1);

    scan_csr<<<1, 1024, 0, stream>>>(deg, row_start, cursor, degf, gsum, NN);

    // prep2: scatter_src || gemm_w2u
    prep2<<<HIST_BLKS + 16 * NL, 256, 0, stream>>>(
        e_src, e_dst, cursor, srcs, u1bT, w2rmb, w2uT);

    // encoder + layer-0 P/Q
    enc_pq<<<NN / 16, 512, 0, stream>>>(nfT, neT1, neT2, ne_b1, ne_b2,
                                        w1tT, w1bT, mb1, x, xb, Pb, Qf, NN);

    for (int l = 0; l < NL; ++l) {
        edge_agg<<<NN / 8, 256, 0, stream>>>(Pb, Qf, row_start, srcs, Haggb);
        int nl = l + 1;
        const ushort_t* pw1t = (nl < NL) ? w1tT + (size_t)nl * HD * HD : nullptr;
        const ushort_t* pw1b = (nl < NL) ? w1bT + (size_t)nl * HD * HD : nullptr;
        const float*    pqb1 = (nl < NL) ? mb1 + (size_t)nl * HD : nullptr;
        float* gs = (l == NL - 1) ? gsum : nullptr;
        upd_ln<<<NN / 16, 512, 0, stream>>>(
            xb, Haggb, u1tT + (size_t)l * HD * HD, w2uT + (size_t)l * HD * HD,
            u2T + (size_t)l * HD * HD, degf,
            ub1 + (size_t)l * HD, b2u1 + (size_t)l * HD, ub2 + (size_t)l * HD,
            lng + (size_t)l * HD, lnb + (size_t)l * HD,
            pw1t, pw1b, pqb1, gs, x, xb, Pb, Qf, NN);
    }

    // readout
    readout_mlp<<<1, 256, 0, stream>>>(gsum, rw1, rb1, rw2, rb2, (float*)d_out, 1.0f / NN);
}

// Round 17
// 268.909 us; speedup vs baseline: 1.1676x; 1.0174x over previous
//
#include <hip/hip_runtime.h>

#define NN 10000
#define NE 320000
#define HD 256
#define NL 3

typedef unsigned short ushort_t;
typedef __attribute__((ext_vector_type(8))) short bf16x8;
typedef __attribute__((ext_vector_type(4))) float f32x4;

#define MFMA __builtin_amdgcn_mfma_f32_16x16x32_bf16

#define WAITV(N) asm volatile("s_waitcnt vmcnt(" #N ")" ::: "memory")
#define SCHEDPIN() __builtin_amdgcn_sched_barrier(0)
#define LGKMBAR() do { asm volatile("s_waitcnt lgkmcnt(0)" ::: "memory"); \
                       __builtin_amdgcn_s_barrier(); __builtin_amdgcn_sched_barrier(0); } while (0)

__device__ __forceinline__ unsigned short f2bf(float x) {
    unsigned u = __float_as_uint(x);
    unsigned rounding = 0x7FFFu + ((u >> 16) & 1u);
    return (unsigned short)((u + rounding) >> 16);
}
__device__ __forceinline__ float bf2f(unsigned short u) {
    return __uint_as_float(((unsigned)u) << 16);
}
__device__ __forceinline__ int sw2(int col) { return (col & 3) ^ ((col >> 2) & 3); }
__device__ __forceinline__ void dma16(const void* g, void* l) {
    __builtin_amdgcn_global_load_lds(
        (const __attribute__((address_space(1))) unsigned int*)g,
        (__attribute__((address_space(3))) unsigned int*)l, 16, 0, 0);
}

// ---------------- prep1: hist_deg || conv_t || cast_nf || bias_compose ----------------

struct TDesc { const float* src; ushort_t* dst; int mode; };
struct TArgs { TDesc d[20]; };

#define HIST_BLKS 1250
#define CONV_BLKS 320
#define CAST_BLKS 625

__global__ __launch_bounds__(256) void prep1(
    const int* __restrict__ edst, int* __restrict__ deg,
    TArgs args,
    const float* __restrict__ nf, ushort_t* __restrict__ nfT,
    const float* __restrict__ mb2, const float* __restrict__ uw1,
    float* __restrict__ b2u1)
{
    __shared__ ushort_t tile[64][65];
    int b = blockIdx.x;
    int tid = threadIdx.x;

    if (b < HIST_BLKS) {                       // ---- hist_deg ----
        int e = b * 256 + tid;
        if (e < NE) atomicAdd(&deg[edst[e]], 1);
        return;
    }
    b -= HIST_BLKS;
    if (b < CONV_BLKS) {                       // ---- conv_t ----
        const float* src = args.d[b >> 4].src;
        ushort_t* dst = args.d[b >> 4].dst;
        int mode = args.d[b >> 4].mode;
        int t = b & 15;
        int r0 = (t >> 2) * 64, c0 = (t & 3) * 64;
        int rr = tid >> 4, cc4 = (tid & 15) * 4;
        if (mode == 0) {
            #pragma unroll
            for (int i = 0; i < 4; ++i) {
                int r = r0 + rr + i * 16;
                float4 v = *(const float4*)(src + (size_t)r * HD + c0 + cc4);
                ushort4 o = { f2bf(v.x), f2bf(v.y), f2bf(v.z), f2bf(v.w) };
                *(ushort4*)(dst + (size_t)r * HD + c0 + cc4) = o;
            }
            return;
        }
        #pragma unroll
        for (int i = 0; i < 4; ++i) {
            int r = rr + i * 16;
            float4 v = *(const float4*)(src + (size_t)(r0 + r) * HD + c0 + cc4);
            tile[cc4 + 0][r] = f2bf(v.x);
            tile[cc4 + 1][r] = f2bf(v.y);
            tile[cc4 + 2][r] = f2bf(v.z);
            tile[cc4 + 3][r] = f2bf(v.w);
        }
        __syncthreads();
        #pragma unroll
        for (int i = 0; i < 4; ++i) {
            int c = rr + i * 16;
            ushort4 o = { tile[c][cc4], tile[c][cc4 + 1], tile[c][cc4 + 2], tile[c][cc4 + 3] };
            if (mode == 1) {
                *(ushort4*)(dst + (size_t)(c0 + c) * HD + r0 + cc4) = o;
            } else {
                int col = c0 + c;
                int k = r0 + cc4;
                int s = k >> 5, qv = (k >> 3) & 3;
                int slot = qv ^ sw2(col);
                *(ushort4*)(dst + (size_t)s * 8192 + col * 32 + slot * 8 + (k & 7)) = o;
            }
        }
        return;
    }
    b -= CONV_BLKS;
    if (b < CAST_BLKS) {                       // ---- cast_nf_tiled ----
        int row = tid >> 4, gg = tid & 15;
        const float* sp = nf + ((size_t)b * 16 + row) * HD + gg * 16;
        ushort_t* dp = nfT + (size_t)b * 4096 + (gg >> 1) * 512 + row * 32 + (gg & 1) * 16;
        #pragma unroll
        for (int j = 0; j < 4; ++j) {
            float4 v = *(const float4*)(sp + j * 4);
            ushort4 o = { f2bf(v.x), f2bf(v.y), f2bf(v.z), f2bf(v.w) };
            *(ushort4*)(dp + j * 4) = o;
        }
        return;
    }
    b -= CAST_BLKS;
    {                                          // ---- bias_compose (NL blocks) ----
        int l = b, c = tid;
        const float* b2l = mb2 + (size_t)l * HD;
        const float* u1b = uw1 + (size_t)l * 2 * HD * HD + (size_t)HD * HD;
        float s = 0.f;
        for (int k = 0; k < HD; ++k) s += b2l[k] * u1b[(size_t)k * HD + c];
        b2u1[(size_t)l * HD + c] = s;
    }
}

// ---------------- prep2: scatter_src || gemm_w2u ----------------

__global__ __launch_bounds__(256) void prep2(
    const int* __restrict__ esrc, const int* __restrict__ edst,
    int* __restrict__ cursor, int* __restrict__ src_sorted,
    const ushort_t* __restrict__ Abase, const ushort_t* __restrict__ Btbase,
    ushort_t* __restrict__ outBase)
{
    int b = blockIdx.x;
    int tid = threadIdx.x;
    if (b < HIST_BLKS) {                       // ---- scatter_src ----
        int e = b * 256 + tid;
        if (e < NE) {
            int pos = atomicAdd(&cursor[edst[e]], 1);
            src_sorted[pos] = esrc[e];
        }
        return;
    }
    int i = b - HIST_BLKS;                     // ---- gemm_w2u (48 blocks) ----
    int bx = i & 3, by = (i >> 2) & 3, bz = i >> 4;
    const ushort_t* A  = Abase  + (size_t)bz * HD * HD;
    const ushort_t* Bt = Btbase + (size_t)bz * HD * HD;
    ushort_t* outB     = outBase + (size_t)bz * HD * HD;
    int wid = tid >> 6, lane = tid & 63;
    int wm = wid >> 1, wn = wid & 1;
    int row0 = bx * 64 + wm * 32;
    int col0 = by * 64 + wn * 32;
    int lm = lane & 15, lk = (lane >> 4) * 8;
    f32x4 acc[2][2] = {};
    const ushort_t* a0p = A + (size_t)(row0 + lm) * HD + lk;
    const ushort_t* a1p = A + (size_t)(row0 + 16 + lm) * HD + lk;
    const ushort_t* b0p = Bt + (size_t)(col0 + lm) * HD + lk;
    const ushort_t* b1p = Bt + (size_t)(col0 + 16 + lm) * HD + lk;
    #pragma unroll
    for (int k0 = 0; k0 < HD; k0 += 32) {
        bf16x8 a0 = *(const bf16x8*)(a0p + k0);
        bf16x8 a1 = *(const bf16x8*)(a1p + k0);
        bf16x8 b0 = *(const bf16x8*)(b0p + k0);
        bf16x8 b1 = *(const bf16x8*)(b1p + k0);
        acc[0][0] = MFMA(a0, b0, acc[0][0], 0, 0, 0);
        acc[0][1] = MFMA(a0, b1, acc[0][1], 0, 0, 0);
        acc[1][0] = MFMA(a1, b0, acc[1][0], 0, 0, 0);
        acc[1][1] = MFMA(a1, b1, acc[1][1], 0, 0, 0);
    }
    int orow = (lane >> 4) * 4;
    #pragma unroll
    for (int mi = 0; mi < 2; ++mi)
        #pragma unroll
        for (int r = 0; r < 4; ++r) {
            int row = row0 + mi * 16 + orow + r;        // n
            #pragma unroll
            for (int ni = 0; ni < 2; ++ni) {
                int col = col0 + ni * 16 + lm;          // k
                int s = col >> 5, qv = (col >> 3) & 3;
                int slot = qv ^ sw2(row);
                outB[(size_t)s * 8192 + row * 32 + slot * 8 + (col & 7)] = f2bf(acc[mi][ni][r]);
            }
        }
}

// ---------------- LDS swizzle for hid [16 rows][512B] ----------------
__device__ __forceinline__ int swz(int row, int byte_in_row) {
    return row * 512 + (byte_in_row ^ ((row & 7) << 4));
}

// ---------------- fused encoder + layer-0 P/Q + embedded CSR scan ----------------
// Blocks 0..624: encoder tiles. Block 625: 512-thread exclusive scan of deg
// (independent of encoder data; hides the single-block scan under enc's 625 blocks).

__global__ __launch_bounds__(512, 4) void enc_pq(
    const ushort_t* __restrict__ Anf, const ushort_t* __restrict__ B1t,
    const ushort_t* __restrict__ B2t,
    const float* __restrict__ b1, const float* __restrict__ b2,
    const ushort_t* __restrict__ Pw1t, const ushort_t* __restrict__ Pw1b,
    const float* __restrict__ pqb1,
    float* __restrict__ xF, ushort_t* __restrict__ xB,
    ushort_t* __restrict__ P, float* __restrict__ Q,
    const int* __restrict__ deg, int* __restrict__ row_start,
    int* __restrict__ cursor, float* __restrict__ degf,
    float* __restrict__ gsum, int M)
{
    __shared__ char wlds[8][2][2][2048];
    __shared__ char hid[16 * 512];
    __shared__ int scn[9];
    int tid = threadIdx.x;

    if (blockIdx.x == NN / 16) {               // ---- embedded scan_csr (512 thr) ----
        int lane = tid & 63, wid = tid >> 6;
        if (tid < HD) gsum[tid] = 0.f;
        if (tid == 0) scn[8] = 0;
        __syncthreads();
        for (int base = 0; base < M; base += 512) {
            int i = base + tid;
            int v = (i < M) ? deg[i] : 0;
            int s = v;
            #pragma unroll
            for (int off = 1; off < 64; off <<= 1) {
                int t = __shfl_up(s, off);
                if (lane >= off) s += t;
            }
            if (lane == 63) scn[wid] = s;
            __syncthreads();
            if (wid == 0 && lane < 8) {
                int ws = scn[lane];
                #pragma unroll
                for (int off = 1; off < 8; off <<= 1) {
                    int t = __shfl_up(ws, off);
                    if (lane >= off) ws += t;
                }
                scn[lane] = ws;
            }
            __syncthreads();
            int carry = scn[8];
            int wpre = (wid > 0) ? scn[wid - 1] : 0;
            int incl = carry + wpre + s;
            int excl = incl - v;
            if (i < M) { row_start[i] = excl; cursor[i] = excl; degf[i] = (float)v; }
            __syncthreads();
            if (tid == 511) scn[8] = incl;
            __syncthreads();
        }
        if (tid == 0) row_start[M] = scn[8];
        return;
    }

    int w = tid >> 6, lane = tid & 63;
    int lm = lane & 15, q = lane >> 4;
    int row0 = blockIdx.x * 16;
    int col0 = w * 32;
    int cA = col0 + lm, cB = col0 + 16 + lm;

    auto stageW = [&](const ushort_t* Wt, int s, int p, int m) {
        #pragma unroll
        for (int i = 0; i < 2; ++i)
            dma16((const char*)Wt + (size_t)s * 16384 + (col0 + 16 * i) * 64 + lane * 16,
                  wlds[w][p][m] + i * 1024);
    };
    auto readB = [&](int p, int m, int ni) -> bf16x8 {
        int col = col0 + 16 * ni + lm;
        int q2 = q ^ sw2(col);
        return *(const bf16x8*)(wlds[w][p][m] + ni * 1024 + lm * 64 + q2 * 16);
    };

    float b1v[2] = { b1[cA], b1[cB] };
    float b2v[2] = { b2[cA], b2[cB] };
    float pqv[2] = { pqb1[cA], pqb1[cB] };

    const ushort_t* ap = Anf + (size_t)blockIdx.x * 4096 + lm * 32 + q * 8;
    bf16x8 ax[2];
    #pragma unroll
    for (int s = 0; s < 2; ++s) {
        stageW(B1t, s, s, 0);
        ax[s] = *(const bf16x8*)(ap + s * 512);
        SCHEDPIN();
    }

    // ---- pass 1: acc = nf @ W1 ----
    f32x4 acc[2] = {};
    #pragma unroll
    for (int j = 0; j < 8; ++j) {
        int p = j & 1;
        if (j < 7) { WAITV(3); } else { WAITV(0); }
        acc[0] = MFMA(ax[p], readB(p, 0, 0), acc[0], 0, 0, 0);
        acc[1] = MFMA(ax[p], readB(p, 0, 1), acc[1], 0, 0, 0);
        SCHEDPIN();
        if (j < 6) {
            stageW(B1t, j + 2, p, 0);
            ax[p] = *(const bf16x8*)(ap + (j + 2) * 512);
            SCHEDPIN();
        }
    }

    #pragma unroll
    for (int s = 0; s < 2; ++s) { stageW(B2t, s, s, 0); SCHEDPIN(); }
    #pragma unroll
    for (int ni = 0; ni < 2; ++ni) {
        int col = col0 + 16 * ni + lm;
        #pragma unroll
        for (int r = 0; r < 4; ++r) {
            int row = 4 * q + r;
            float v = fmaxf(acc[ni][r] + b1v[ni], 0.f);
            *(ushort_t*)(hid + swz(row, col * 2)) = f2bf(v);
        }
    }
    LGKMBAR();

    // ---- pass 2: acc2 = hid @ W2 ----
    f32x4 acc2[2] = {};
    #pragma unroll
    for (int j = 0; j < 8; ++j) {
        int p = j & 1;
        if (j < 7) { WAITV(2); } else { WAITV(0); }
        int bk = (j * 32 + q * 8) * 2;
        bf16x8 a = *(const bf16x8*)(hid + swz(lm, bk));
        acc2[0] = MFMA(a, readB(p, 0, 0), acc2[0], 0, 0, 0);
        acc2[1] = MFMA(a, readB(p, 0, 1), acc2[1], 0, 0, 0);
        SCHEDPIN();
        if (j < 6) { stageW(B2t, j + 2, p, 0); SCHEDPIN(); }
    }

    // PQ prologue; xstage after all pass-2 hid reads
    #pragma unroll
    for (int s = 0; s < 2; ++s) {
        stageW(Pw1t, s, s, 0);
        stageW(Pw1b, s, s, 1);
        SCHEDPIN();
    }
    LGKMBAR();
    int tbase = blockIdx.x * 4096 + w * 512;
    #pragma unroll
    for (int ni = 0; ni < 2; ++ni) {
        int col = col0 + 16 * ni + lm;
        #pragma unroll
        for (int r = 0; r < 4; ++r) {
            int row = 4 * q + r;
            int grow = row0 + row;
            float v = acc2[ni][r] + b2v[ni];
            *(ushort_t*)(hid + swz(row, col * 2)) = f2bf(v);
            xF[(size_t)grow * HD + col] = v;
            xB[tbase + row * 32 + 16 * ni + lm] = f2bf(v);
        }
    }
    LGKMBAR();

    // ---- PQ pass ----
    f32x4 aP[2] = {}, aQ[2] = {};
    #pragma unroll
    for (int j = 0; j < 8; ++j) {
        int p = j & 1;
        if (j < 7) { WAITV(4); } else { WAITV(0); }
        int bk = (j * 32 + q * 8) * 2;
        bf16x8 a = *(const bf16x8*)(hid + swz(lm, bk));
        #pragma unroll
        for (int ni = 0; ni < 2; ++ni) {
            aP[ni] = MFMA(a, readB(p, 0, ni), aP[ni], 0, 0, 0);
            aQ[ni] = MFMA(a, readB(p, 1, ni), aQ[ni], 0, 0, 0);
        }
        SCHEDPIN();
        if (j < 6) {
            stageW(Pw1t, j + 2, p, 0);
            stageW(Pw1b, j + 2, p, 1);
            SCHEDPIN();
        }
    }
    #pragma unroll
    for (int r = 0; r < 4; ++r) {
        int grow = row0 + 4 * q + r;
        #pragma unroll
        for (int ni = 0; ni < 2; ++ni) {
            int col = col0 + 16 * ni + lm;
            P[(size_t)grow * HD + col] = f2bf(aP[ni][r]);
            Q[(size_t)grow * HD + col] = aQ[ni][r] + pqv[ni];
        }
    }
}

// ---------------- edge aggregation (2 nodes/wave, interleaved streams) ----------------

__global__ __launch_bounds__(256) void edge_agg(
    const ushort_t* __restrict__ Pb, const float* __restrict__ Qf,
    const int* __restrict__ row_start, const int* __restrict__ srcs,
    ushort_t* __restrict__ HaggT)
{
    int wv = blockIdx.x * 4 + (threadIdx.x >> 6);
    int lane = threadIdx.x & 63;
    int c4 = lane * 4;
    int n0 = wv * 2, n1 = n0 + 1;
    float4 qb0 = *(const float4*)(Qf + (size_t)n0 * HD + c4);
    float4 qb1 = *(const float4*)(Qf + (size_t)n1 * HD + c4);
    float4 A0 = {0.f, 0.f, 0.f, 0.f}, A1 = {0.f, 0.f, 0.f, 0.f};
    int j0 = row_start[n0], e0 = row_start[n0 + 1];
    int j1 = row_start[n1], e1 = row_start[n1 + 1];
    while (j0 + 4 <= e0 && j1 + 4 <= e1) {
        ushort4 p[8];
        #pragma unroll
        for (int u = 0; u < 4; ++u)
            p[u] = *(const ushort4*)(Pb + (size_t)srcs[j0 + u] * HD + c4);
        #pragma unroll
        for (int u = 0; u < 4; ++u)
            p[4 + u] = *(const ushort4*)(Pb + (size_t)srcs[j1 + u] * HD + c4);
        #pragma unroll
        for (int u = 0; u < 4; ++u) {
            A0.x += fmaxf(bf2f(p[u].x) + qb0.x, 0.f);
            A0.y += fmaxf(bf2f(p[u].y) + qb0.y, 0.f);
            A0.z += fmaxf(bf2f(p[u].z) + qb0.z, 0.f);
            A0.w += fmaxf(bf2f(p[u].w) + qb0.w, 0.f);
            A1.x += fmaxf(bf2f(p[4 + u].x) + qb1.x, 0.f);
            A1.y += fmaxf(bf2f(p[4 + u].y) + qb1.y, 0.f);
            A1.z += fmaxf(bf2f(p[4 + u].z) + qb1.z, 0.f);
            A1.w += fmaxf(bf2f(p[4 + u].w) + qb1.w, 0.f);
        }
        j0 += 4; j1 += 4;
    }
    for (; j0 + 4 <= e0; j0 += 4) {
        ushort4 p[4];
        #pragma unroll
        for (int u = 0; u < 4; ++u)
            p[u] = *(const ushort4*)(Pb + (size_t)srcs[j0 + u] * HD + c4);
        #pragma unroll
        for (int u = 0; u < 4; ++u) {
            A0.x += fmaxf(bf2f(p[u].x) + qb0.x, 0.f);
            A0.y += fmaxf(bf2f(p[u].y) + qb0.y, 0.f);
            A0.z += fmaxf(bf2f(p[u].z) + qb0.z, 0.f);
            A0.w += fmaxf(bf2f(p[u].w) + qb0.w, 0.f);
        }
    }
    for (; j0 < e0; ++j0) {
        ushort4 p0 = *(const ushort4*)(Pb + (size_t)srcs[j0] * HD + c4);
        A0.x += fmaxf(bf2f(p0.x) + qb0.x, 0.f);
        A0.y += fmaxf(bf2f(p0.y) + qb0.y, 0.f);
        A0.z += fmaxf(bf2f(p0.z) + qb0.z, 0.f);
        A0.w += fmaxf(bf2f(p0.w) + qb0.w, 0.f);
    }
    for (; j1 + 4 <= e1; j1 += 4) {
        ushort4 p[4];
        #pragma unroll
        for (int u = 0; u < 4; ++u)
            p[u] = *(const ushort4*)(Pb + (size_t)srcs[j1 + u] * HD + c4);
        #pragma unroll
        for (int u = 0; u < 4; ++u) {
            A1.x += fmaxf(bf2f(p[u].x) + qb1.x, 0.f);
            A1.y += fmaxf(bf2f(p[u].y) + qb1.y, 0.f);
            A1.z += fmaxf(bf2f(p[u].z) + qb1.z, 0.f);
            A1.w += fmaxf(bf2f(p[u].w) + qb1.w, 0.f);
        }
    }
    for (; j1 < e1; ++j1) {
        ushort4 p0 = *(const ushort4*)(Pb + (size_t)srcs[j1] * HD + c4);
        A1.x += fmaxf(bf2f(p0.x) + qb1.x, 0.f);
        A1.y += fmaxf(bf2f(p0.y) + qb1.y, 0.f);
        A1.z += fmaxf(bf2f(p0.z) + qb1.z, 0.f);
        A1.w += fmaxf(bf2f(p0.w) + qb1.w, 0.f);
    }
    ushort4 o0 = { f2bf(A0.x), f2bf(A0.y), f2bf(A0.z), f2bf(A0.w) };
    ushort4 o1 = { f2bf(A1.x), f2bf(A1.y), f2bf(A1.z), f2bf(A1.w) };
    int t0 = (n0 >> 4) * 4096 + (c4 >> 5) * 512 + (n0 & 15) * 32 + (c4 & 31);
    int t1 = (n1 >> 4) * 4096 + (c4 >> 5) * 512 + (n1 & 15) * 32 + (c4 & 31);
    *(ushort4*)(HaggT + t0) = o0;
    *(ushort4*)(HaggT + t1) = o1;
}

// ---------------- fused update + LN + next P/Q (tiled operands, contiguous DMA) ----------------

__global__ __launch_bounds__(512, 4) void upd_ln(
    const ushort_t* __restrict__ xb, const ushort_t* __restrict__ Hb,
    const ushort_t* __restrict__ B1t, const ushort_t* __restrict__ B2t,
    const ushort_t* __restrict__ B3t,
    const float* __restrict__ degf,
    const float* __restrict__ b1, const float* __restrict__ bias2,
    const float* __restrict__ b3,
    const float* __restrict__ g, const float* __restrict__ bb,
    const ushort_t* __restrict__ Pw1t, const ushort_t* __restrict__ Pw1b,
    const float* __restrict__ pqb1,
    float* __restrict__ gsum,
    float* __restrict__ xF, ushort_t* __restrict__ xB,
    ushort_t* __restrict__ P, float* __restrict__ Q, int M)
{
    __shared__ char wlds[8][2][2][2048];
    __shared__ char hid[16 * 512];
    __shared__ float sS[8][16], sQ[8][16], muv[16], ivv[16];

    int tid = threadIdx.x;
    int w = tid >> 6, lane = tid & 63;
    int lm = lane & 15, q = lane >> 4;
    int row0 = blockIdx.x * 16;
    int col0 = w * 32;
    int cA = col0 + lm, cB = col0 + 16 + lm;

    auto stageW = [&](const ushort_t* Wt, int s, int p, int m) {
        #pragma unroll
        for (int i = 0; i < 2; ++i)
            dma16((const char*)Wt + (size_t)s * 16384 + (col0 + 16 * i) * 64 + lane * 16,
                  wlds[w][p][m] + i * 1024);
    };
    auto readB = [&](int p, int m, int ni) -> bf16x8 {
        int col = col0 + 16 * ni + lm;
        int q2 = q ^ sw2(col);
        return *(const bf16x8*)(wlds[w][p][m] + ni * 1024 + lm * 64 + q2 * 16);
    };

    const ushort_t* xp = xb + (size_t)blockIdx.x * 4096 + lm * 32 + q * 8;
    const ushort_t* hp = Hb + (size_t)blockIdx.x * 4096 + lm * 32 + q * 8;
    bf16x8 ax[2], ah[2];
    #pragma unroll
    for (int s = 0; s < 2; ++s) {
        stageW(B1t, s, s, 0);
        stageW(B2t, s, s, 1);
        ax[s] = *(const bf16x8*)(xp + s * 512);
        ah[s] = *(const bf16x8*)(hp + s * 512);
        SCHEDPIN();
    }

    float b1v[2] = { b1[cA], b1[cB] };
    float bzv[2] = { bias2[cA], bias2[cB] };
    float b3v[2] = { b3[cA], b3[cB] };
    float gv[2]  = { g[cA],  g[cB]  };
    float bbv[2] = { bb[cA], bb[cB] };
    float pqv[2] = { Pw1t ? pqb1[cA] : 0.f, Pw1t ? pqb1[cB] : 0.f };
    float dgv[4], res[2][4];
    #pragma unroll
    for (int r = 0; r < 4; ++r) {
        int row = 4 * q + r;
        dgv[r] = degf[row0 + row];
        res[0][r] = xF[(size_t)(row0 + row) * HD + cA];
        res[1][r] = xF[(size_t)(row0 + row) * HD + cB];
    }

    // ---- pass 1+2: acc = x@u1t + Hagg@w2u ----
    f32x4 acc[2] = {};
    #pragma unroll
    for (int j = 0; j < 8; ++j) {
        int p = j & 1;
        if (j < 7) { WAITV(6); } else { WAITV(0); }
        #pragma unroll
        for (int ni = 0; ni < 2; ++ni) {
            acc[ni] = MFMA(ax[p], readB(p, 0, ni), acc[ni], 0, 0, 0);
            acc[ni] = MFMA(ah[p], readB(p, 1, ni), acc[ni], 0, 0, 0);
        }
        SCHEDPIN();
        if (j < 6) {
            stageW(B1t, j + 2, p, 0);
            stageW(B2t, j + 2, p, 1);
            ax[p] = *(const bf16x8*)(xp + (j + 2) * 512);
            ah[p] = *(const bf16x8*)(hp + (j + 2) * 512);
            SCHEDPIN();
        }
    }

    // transition: u2 prologue over hid build
    #pragma unroll
    for (int s = 0; s < 2; ++s) { stageW(B3t, s, s, 0); SCHEDPIN(); }
    #pragma unroll
    for (int r = 0; r < 4; ++r) {
        int row = 4 * q + r;
        #pragma unroll
        for (int ni = 0; ni < 2; ++ni) {
            int col = col0 + 16 * ni + lm;
            float v = fmaxf(acc[ni][r] + b1v[ni] + dgv[r] * bzv[ni], 0.f);
            *(ushort_t*)(hid + swz(row, col * 2)) = f2bf(v);
        }
    }
    LGKMBAR();

    // ---- pass 3: upd = hid @ u2 ----
    f32x4 acc2[2] = {};
    #pragma unroll
    for (int j = 0; j < 8; ++j) {
        int p = j & 1;
        if (j < 7) { WAITV(2); } else { WAITV(0); }
        int bk = (j * 32 + q * 8) * 2;
        bf16x8 a = *(const bf16x8*)(hid + swz(lm, bk));
        acc2[0] = MFMA(a, readB(p, 0, 0), acc2[0], 0, 0, 0);
        acc2[1] = MFMA(a, readB(p, 0, 1), acc2[1], 0, 0, 0);
        SCHEDPIN();
        if (j < 6) { stageW(B3t, j + 2, p, 0); SCHEDPIN(); }
    }

    // PQ prologue over LN
    if (Pw1t) {
        #pragma unroll
        for (int s = 0; s < 2; ++s) {
            stageW(Pw1t, s, s, 0);
            stageW(Pw1b, s, s, 1);
            SCHEDPIN();
        }
    }
    // v = x + upd + ub2; LN partials
    #pragma unroll
    for (int r = 0; r < 4; ++r) {
        float s = 0.f, qq = 0.f;
        #pragma unroll
        for (int ni = 0; ni < 2; ++ni) {
            float v = acc2[ni][r] + b3v[ni] + res[ni][r];
            acc2[ni][r] = v;
            s += v; qq += v * v;
        }
        #pragma unroll
        for (int off = 1; off < 16; off <<= 1) {
            s += __shfl_xor(s, off);
            qq += __shfl_xor(qq, off);
        }
        if (lm == 0) {
            int row = 4 * q + r;
            sS[w][row] = s; sQ[w][row] = qq;
        }
    }
    LGKMBAR();
    if (tid < 16) {
        float s = 0.f, qq = 0.f;
        #pragma unroll
        for (int i = 0; i < 8; ++i) { s += sS[i][tid]; qq += sQ[i][tid]; }
        float mu = s * (1.0f / HD);
        float var = qq * (1.0f / HD) - mu * mu;
        muv[tid] = mu;
        ivv[tid] = rsqrtf(var + 1e-5f);
    }
    LGKMBAR();
    // LN final + stores + xstage + colsum partials
    float csum[2] = {0.f, 0.f};
    int tbase = blockIdx.x * 4096 + w * 512;
    #pragma unroll
    for (int r = 0; r < 4; ++r) {
        int row = 4 * q + r;
        int grow = row0 + row;
        float mu = muv[row], iv = ivv[row];
        #pragma unroll
        for (int ni = 0; ni < 2; ++ni) {
            int col = col0 + 16 * ni + lm;
            float o = (acc2[ni][r] - mu) * iv * gv[ni] + bbv[ni];
            *(ushort_t*)(hid + swz(row, col * 2)) = f2bf(o);
            xF[(size_t)grow * HD + col] = o;
            xB[tbase + row * 32 + 16 * ni + lm] = f2bf(o);
            csum[ni] += o;
        }
    }
    if (gsum) {
        #pragma unroll
        for (int ni = 0; ni < 2; ++ni) {
            float s = csum[ni];
            s += __shfl_xor(s, 16);
            s += __shfl_xor(s, 32);
            if (q == 0) atomicAdd(&gsum[col0 + 16 * ni + lm], s);
        }
    }

    // ---- PQ pass ----
    if (Pw1t) {
        LGKMBAR();
        f32x4 aP[2] = {}, aQ[2] = {};
        #pragma unroll
        for (int j = 0; j < 8; ++j) {
            int p = j & 1;
            if (j < 7) { WAITV(4); } else { WAITV(0); }
            int bk = (j * 32 + q * 8) * 2;
            bf16x8 a = *(const bf16x8*)(hid + swz(lm, bk));
            #pragma unroll
            for (int ni = 0; ni < 2; ++ni) {
                aP[ni] = MFMA(a, readB(p, 0, ni), aP[ni], 0, 0, 0);
                aQ[ni] = MFMA(a, readB(p, 1, ni), aQ[ni], 0, 0, 0);
            }
            SCHEDPIN();
            if (j < 6) {
                stageW(Pw1t, j + 2, p, 0);
                stageW(Pw1b, j + 2, p, 1);
                SCHEDPIN();
            }
        }
        #pragma unroll
        for (int r = 0; r < 4; ++r) {
            int grow = row0 + 4 * q + r;
            #pragma unroll
            for (int ni = 0; ni < 2; ++ni) {
                int col = col0 + 16 * ni + lm;
                P[(size_t)grow * HD + col] = f2bf(aP[ni][r]);
                Q[(size_t)grow * HD + col] = aQ[ni][r] + pqv[ni];
            }
        }
    }
}

// ---------------- readout ----------------

__global__ __launch_bounds__(256) void readout_mlp(
    const float* __restrict__ gsum,
    const float* __restrict__ w1, const float* __restrict__ b1,
    const float* __restrict__ w2, const float* __restrict__ b2,
    float* __restrict__ out, float invn)
{
    __shared__ float gl[HD], h1[HD];
    int c = threadIdx.x;
    gl[c] = gsum[c] * invn;
    __syncthreads();
    float a = b1[c];
    for (int k = 0; k < HD; ++k) a += gl[k] * w1[k * HD + c];
    h1[c] = fmaxf(a, 0.f);
    __syncthreads();
    float o = b2[c];
    for (int k = 0; k < HD; ++k) o += h1[k] * w2[k * HD + c];
    out[c] = o;
}

// ---------------- orchestration ----------------

extern "C" void kernel_launch(void* const* d_in, const int* in_sizes, int n_in,
                              void* d_out, int out_size, void* d_ws, size_t ws_size,
                              hipStream_t stream) {
    const float* nf    = (const float*)d_in[0];
    const int*   ei    = (const int*)d_in[1];
    const float* ne_w1 = (const float*)d_in[2];
    const float* ne_b1 = (const float*)d_in[3];
    const float* ne_w2 = (const float*)d_in[4];
    const float* ne_b2 = (const float*)d_in[5];
    const float* mw1   = (const float*)d_in[6];
    const float* mb1   = (const float*)d_in[7];
    const float* mw2   = (const float*)d_in[8];
    const float* mb2   = (const float*)d_in[9];
    const float* uw1   = (const float*)d_in[10];
    const float* ub1   = (const float*)d_in[11];
    const float* uw2   = (const float*)d_in[12];
    const float* ub2   = (const float*)d_in[13];
    const float* lng   = (const float*)d_in[14];
    const float* lnb   = (const float*)d_in[15];
    const float* rw1   = (const float*)d_in[16];
    const float* rb1   = (const float*)d_in[17];
    const float* rw2   = (const float*)d_in[18];
    const float* rb2   = (const float*)d_in[19];

    const int* e_src = ei;
    const int* e_dst = ei + NE;

    char* w = (char*)d_ws;
    size_t off = 0;
    auto alloc = [&](size_t bytes) -> void* {
        void* p = w + off;
        off = (off + bytes + 255) & ~(size_t)255;
        return p;
    };
    const size_t NF32 = (size_t)NN * HD * sizeof(float);
    const size_t NF16 = (size_t)NN * HD * sizeof(ushort_t);
    const size_t WM16 = (size_t)HD * HD * sizeof(ushort_t);

    float* x    = (float*)alloc(NF32);
    float* Qf   = (float*)alloc(NF32);
    float* gsum = (float*)alloc(HD * sizeof(float));
    float* degf = (float*)alloc(NN * sizeof(float));
    float* b2u1 = (float*)alloc(NL * HD * sizeof(float));

    ushort_t* nfT   = (ushort_t*)alloc(NF16);
    ushort_t* xb    = (ushort_t*)alloc(NF16);
    ushort_t* Pb    = (ushort_t*)alloc(NF16);
    ushort_t* Haggb = (ushort_t*)alloc(NF16);
    ushort_t* neT1  = (ushort_t*)alloc(WM16);
    ushort_t* neT2  = (ushort_t*)alloc(WM16);
    ushort_t* w1tT  = (ushort_t*)alloc(NL * WM16);
    ushort_t* w1bT  = (ushort_t*)alloc(NL * WM16);
    ushort_t* u1tT  = (ushort_t*)alloc(NL * WM16);
    ushort_t* u1bT  = (ushort_t*)alloc(NL * WM16);
    ushort_t* u2T   = (ushort_t*)alloc(NL * WM16);
    ushort_t* w2uT  = (ushort_t*)alloc(NL * WM16);
    ushort_t* w2rmb = (ushort_t*)alloc(NL * WM16);

    int* deg       = (int*)alloc(NN * sizeof(int));
    int* row_start = (int*)alloc((NN + 1) * sizeof(int));
    int* cursor    = (int*)alloc(NN * sizeof(int));
    int* srcs      = (int*)alloc(NE * sizeof(int));

    hipMemsetAsync(deg, 0, NN * sizeof(int), stream);

    // prep1: hist_deg || conv_t (20 mats) || cast_nf || bias_compose
    TArgs ta;
    ta.d[0] = { ne_w1, neT1, 2 };
    ta.d[1] = { ne_w2, neT2, 2 };
    for (int l = 0; l < NL; ++l) {
        const float* w1l = mw1 + (size_t)l * 2 * HD * HD;
        const float* u1l = uw1 + (size_t)l * 2 * HD * HD;
        ta.d[2 + l]  = { w1l,                       w1tT + (size_t)l * HD * HD, 2 };
        ta.d[5 + l]  = { w1l + (size_t)HD * HD,     w1bT + (size_t)l * HD * HD, 2 };
        ta.d[8 + l]  = { u1l,                       u1tT + (size_t)l * HD * HD, 2 };
        ta.d[11 + l] = { u1l + (size_t)HD * HD,     u1bT + (size_t)l * HD * HD, 1 };
        ta.d[14 + l] = { uw2 + (size_t)l * HD * HD, u2T + (size_t)l * HD * HD, 2 };
        ta.d[17 + l] = { mw2 + (size_t)l * HD * HD, w2rmb + (size_t)l * HD * HD, 0 };
    }
    prep1<<<HIST_BLKS + CONV_BLKS + CAST_BLKS + NL, 256, 0, stream>>>(
        e_dst, deg, ta, nf, nfT, mb2, uw1, b2u1);

    // encoder + layer-0 P/Q, with CSR scan embedded as block NN/16
    enc_pq<<<NN / 16 + 1, 512, 0, stream>>>(nfT, neT1, neT2, ne_b1, ne_b2,
                                            w1tT, w1bT, mb1, x, xb, Pb, Qf,
                                            deg, row_start, cursor, degf, gsum, NN);

    // prep2: scatter_src || gemm_w2u (needs scan's cursor + prep1's bf16 mats)
    prep2<<<HIST_BLKS + 16 * NL, 256, 0, stream>>>(
        e_src, e_dst, cursor, srcs, u1bT, w2rmb, w2uT);

    for (int l = 0; l < NL; ++l) {
        edge_agg<<<NN / 8, 256, 0, stream>>>(Pb, Qf, row_start, srcs, Haggb);
        int nl = l + 1;
        const ushort_t* pw1t = (nl < NL) ? w1tT + (size_t)nl * HD * HD : nullptr;
        const ushort_t* pw1b = (nl < NL) ? w1bT + (size_t)nl * HD * HD : nullptr;
        const float*    pqb1 = (nl < NL) ? mb1 + (size_t)nl * HD : nullptr;
        float* gs = (l == NL - 1) ? gsum : nullptr;
        upd_ln<<<NN / 16, 512, 0, stream>>>(
            xb, Haggb, u1tT + (size_t)l * HD * HD, w2uT + (size_t)l * HD * HD,
            u2T + (size_t)l * HD * HD, degf,
            ub1 + (size_t)l * HD, b2u1 + (size_t)l * HD, ub2 + (size_t)l * HD,
            lng + (size_t)l * HD, lnb + (size_t)l * HD,
            pw1t, pw1b, pqb1, gs, x, xb, Pb, Qf, NN);
    }

    // readout
    readout_mlp<<<1, 256, 0, stream>>>(gsum, rw1, rb1, rw2, rb2, (float*)d_out, 1.0f / NN);
}